// Round 1
// baseline (609.612 us; speedup 1.0000x reference)
//
#include <hip/hip_runtime.h>

#define HW 2304
#define WID 48

// ---------------- Projection: out[n][oc] = bias[oc] + sum_c in[c][n] * w[oc*192+c]
// in slab: [192][HW] (channel-major), out slab: [HW][out_stride] at +out_off
__global__ __launch_bounds__(256) void proj_kernel(
    const float* __restrict__ in, const float* __restrict__ w,
    const float* __restrict__ bias, float* __restrict__ out,
    int out_stride, int out_off)
{
  __shared__ float in_lds[192 * 33];
  const float* inb = in + (size_t)blockIdx.y * 192 * HW;
  float* outb = out + (size_t)blockIdx.y * HW * out_stride;
  const int n0 = blockIdx.x * 32;
  const int t = threadIdx.x;

  for (int idx = t; idx < 192 * 32; idx += 256) {
    int c = idx >> 5, ni = idx & 31;
    in_lds[c * 33 + ni] = inb[(size_t)c * HW + n0 + ni];
  }
  __syncthreads();

  const int ni = t & 31;
  const int grp = t >> 5;  // 0..7, each does 24 output channels
  for (int ch = 0; ch < 6; ++ch) {
    const int oc0 = grp * 24 + ch * 4;
    float a0 = bias[oc0 + 0], a1 = bias[oc0 + 1], a2 = bias[oc0 + 2], a3 = bias[oc0 + 3];
    const float* wr = w + (size_t)oc0 * 192;
#pragma unroll 4
    for (int c = 0; c < 192; c += 4) {
      float v0 = in_lds[(c + 0) * 33 + ni];
      float v1 = in_lds[(c + 1) * 33 + ni];
      float v2 = in_lds[(c + 2) * 33 + ni];
      float v3 = in_lds[(c + 3) * 33 + ni];
      float4 wa = *(const float4*)(wr + c);
      float4 wb = *(const float4*)(wr + 192 + c);
      float4 wc = *(const float4*)(wr + 384 + c);
      float4 wd = *(const float4*)(wr + 576 + c);
      a0 += v0 * wa.x + v1 * wa.y + v2 * wa.z + v3 * wa.w;
      a1 += v0 * wb.x + v1 * wb.y + v2 * wb.z + v3 * wb.w;
      a2 += v0 * wc.x + v1 * wc.y + v2 * wc.z + v3 * wc.w;
      a3 += v0 * wd.x + v1 * wd.y + v2 * wd.z + v3 * wd.w;
    }
    float4 r; r.x = a0; r.y = a1; r.z = a2; r.w = a3;
    *(float4*)(outb + (size_t)(n0 + ni) * out_stride + out_off + oc0) = r;
  }
}

// ---------------- Deformable attention: one thread per (b, n, head-pair p)
// qp: [B][HW][192], kv: [B*2][HW][384] (0..191 k-proj, 192..383 v-proj)
// offs: [B][2][216][HW], o_ws: [B][HW][192]
__global__ __launch_bounds__(256) void attn_kernel(
    const float* __restrict__ qp, const float* __restrict__ kv,
    const float* __restrict__ offs, float* __restrict__ o_ws)
{
  __shared__ float sc_lds[256 * 37];
  const int t = threadIdx.x;
  const int gid = blockIdx.x * 256 + t;
  const int n = gid % HW;
  const int rem = gid / HW;
  const int p = rem % 6;
  const int b = rem / 6;
  const int hh = n / WID, ww = n % WID;
  float* sc = &sc_lds[t * 37];  // 36 scores: [(c*9+kk)*2 + head]

  float qv[32];
  {
    const float4* q4 = (const float4*)(qp + ((size_t)b * HW + n) * 192 + p * 32);
#pragma unroll
    for (int i = 0; i < 8; ++i) {
      float4 v = q4[i];
      qv[4 * i + 0] = v.x * 0.25f; qv[4 * i + 1] = v.y * 0.25f;
      qv[4 * i + 2] = v.z * 0.25f; qv[4 * i + 3] = v.w * 0.25f;
    }
  }

  // ---- K phase: scores for heads 2p, 2p+1 over (clip, tap)
  for (int c = 0; c < 2; ++c) {
    const float* offb = offs + ((size_t)(b * 2 + c)) * 216 * HW + n;
    const float* kvb = kv + ((size_t)(b * 2 + c)) * HW * 384;
    for (int kk = 0; kk < 9; ++kk) {
      float oy = offb[(size_t)((p * 9 + kk) * 2 + 0) * HW];
      float ox = offb[(size_t)((p * 9 + kk) * 2 + 1) * HW];
      float py = (float)(hh - 1 + kk / 3) + oy;
      float px = (float)(ww - 1 + kk % 3) + ox;
      float y0f = floorf(py), x0f = floorf(px);
      int y0 = (int)y0f, x0 = (int)x0f;
      float wy1 = py - y0f, wx1 = px - x0f;
      float wy0 = 1.f - wy1, wx0 = 1.f - wx1;
      float s0 = 0.f, s1 = 0.f;
#pragma unroll
      for (int cy = 0; cy < 2; ++cy) {
        int yi = y0 + cy;
        float wyv = cy ? wy1 : wy0;
#pragma unroll
        for (int cx = 0; cx < 2; ++cx) {
          int xi = x0 + cx;
          float wgt = wyv * (cx ? wx1 : wx0);
          if (!((unsigned)yi < 48u && (unsigned)xi < 48u)) wgt = 0.f;
          int yc = yi < 0 ? 0 : (yi > 47 ? 47 : yi);
          int xc = xi < 0 ? 0 : (xi > 47 ? 47 : xi);
          const float4* row = (const float4*)(kvb + (size_t)(yc * WID + xc) * 384 + p * 32);
          float d0 = 0.f, d1 = 0.f;
#pragma unroll
          for (int i = 0; i < 4; ++i) {
            float4 vv = row[i];
            d0 += qv[4 * i + 0] * vv.x + qv[4 * i + 1] * vv.y + qv[4 * i + 2] * vv.z + qv[4 * i + 3] * vv.w;
          }
#pragma unroll
          for (int i = 4; i < 8; ++i) {
            float4 vv = row[i];
            d1 += qv[4 * i + 0] * vv.x + qv[4 * i + 1] * vv.y + qv[4 * i + 2] * vv.z + qv[4 * i + 3] * vv.w;
          }
          s0 += wgt * d0; s1 += wgt * d1;
        }
      }
      sc[(c * 9 + kk) * 2 + 0] = s0;
      sc[(c * 9 + kk) * 2 + 1] = s1;
    }
  }

  // ---- softmax per head over 18 taps
#pragma unroll
  for (int e = 0; e < 2; ++e) {
    float m = -1e30f;
    for (int j = 0; j < 18; ++j) m = fmaxf(m, sc[j * 2 + e]);
    float sum = 0.f;
    for (int j = 0; j < 18; ++j) { float ev = __expf(sc[j * 2 + e] - m); sc[j * 2 + e] = ev; sum += ev; }
    float inv = 1.f / sum;
    for (int j = 0; j < 18; ++j) sc[j * 2 + e] *= inv;
  }

  // ---- V phase: weighted accumulation (v groups are p+6, different offsets!)
  float acc[32];
#pragma unroll
  for (int i = 0; i < 32; ++i) acc[i] = 0.f;
  for (int c = 0; c < 2; ++c) {
    const float* offb = offs + ((size_t)(b * 2 + c)) * 216 * HW + n;
    const float* kvb = kv + ((size_t)(b * 2 + c)) * HW * 384;
    for (int kk = 0; kk < 9; ++kk) {
      float oy = offb[(size_t)(((p + 6) * 9 + kk) * 2 + 0) * HW];
      float ox = offb[(size_t)(((p + 6) * 9 + kk) * 2 + 1) * HW];
      float py = (float)(hh - 1 + kk / 3) + oy;
      float px = (float)(ww - 1 + kk % 3) + ox;
      float y0f = floorf(py), x0f = floorf(px);
      int y0 = (int)y0f, x0 = (int)x0f;
      float wy1 = py - y0f, wx1 = px - x0f;
      float wy0 = 1.f - wy1, wx0 = 1.f - wx1;
      float a0 = sc[(c * 9 + kk) * 2 + 0];
      float a1 = sc[(c * 9 + kk) * 2 + 1];
#pragma unroll
      for (int cy = 0; cy < 2; ++cy) {
        int yi = y0 + cy;
        float wyv = cy ? wy1 : wy0;
#pragma unroll
        for (int cx = 0; cx < 2; ++cx) {
          int xi = x0 + cx;
          float wgt = wyv * (cx ? wx1 : wx0);
          if (!((unsigned)yi < 48u && (unsigned)xi < 48u)) wgt = 0.f;
          int yc = yi < 0 ? 0 : (yi > 47 ? 47 : yi);
          int xc = xi < 0 ? 0 : (xi > 47 ? 47 : xi);
          const float4* row = (const float4*)(kvb + (size_t)(yc * WID + xc) * 384 + 192 + p * 32);
          float c0 = wgt * a0, c1 = wgt * a1;
#pragma unroll
          for (int i = 0; i < 4; ++i) {
            float4 vv = row[i];
            acc[4 * i + 0] += c0 * vv.x; acc[4 * i + 1] += c0 * vv.y;
            acc[4 * i + 2] += c0 * vv.z; acc[4 * i + 3] += c0 * vv.w;
          }
#pragma unroll
          for (int i = 4; i < 8; ++i) {
            float4 vv = row[i];
            acc[4 * i + 0] += c1 * vv.x; acc[4 * i + 1] += c1 * vv.y;
            acc[4 * i + 2] += c1 * vv.z; acc[4 * i + 3] += c1 * vv.w;
          }
        }
      }
    }
  }

  float* orow = o_ws + ((size_t)b * HW + n) * 192 + p * 32;
#pragma unroll
  for (int i = 0; i < 8; ++i) {
    float4 r; r.x = acc[4 * i]; r.y = acc[4 * i + 1]; r.z = acc[4 * i + 2]; r.w = acc[4 * i + 3];
    *(float4*)(orow + 4 * i) = r;
  }
}

// ---------------- MLP + residual: out[b][oc][n] = o[b][n][oc] + w2 @ gelu(w1 @ o + b1) + b2
__global__ __launch_bounds__(256) void mlp_kernel(
    const float* __restrict__ o_ws, const float* __restrict__ w1, const float* __restrict__ b1,
    const float* __restrict__ w2, const float* __restrict__ b2, float* __restrict__ out)
{
  __shared__ float o_lds[16 * 193];
  __shared__ float h_lds[16 * 385];
  const int blk = blockIdx.x;
  const int b = blk / 144;
  const int n0 = (blk % 144) * 16;
  const int t = threadIdx.x;

  const float4* src = (const float4*)(o_ws + ((size_t)b * HW + n0) * 192);
  for (int idx = t; idx < 768; idx += 256) {
    int r = idx / 48, c4 = idx % 48;
    float4 v = src[r * 48 + c4];
    float* dst = &o_lds[r * 193 + c4 * 4];
    dst[0] = v.x; dst[1] = v.y; dst[2] = v.z; dst[3] = v.w;
  }
  __syncthreads();

  const int ni = t & 15;
  const int grp = t >> 4;  // 0..15

  // GEMM1: 384 outputs, 24 per group
  for (int ch = 0; ch < 6; ++ch) {
    const int oc0 = grp * 24 + ch * 4;
    float a0 = b1[oc0 + 0], a1 = b1[oc0 + 1], a2 = b1[oc0 + 2], a3 = b1[oc0 + 3];
    const float* wr = w1 + (size_t)oc0 * 192;
#pragma unroll 4
    for (int c = 0; c < 192; c += 4) {
      float v0 = o_lds[ni * 193 + c + 0];
      float v1 = o_lds[ni * 193 + c + 1];
      float v2 = o_lds[ni * 193 + c + 2];
      float v3 = o_lds[ni * 193 + c + 3];
      float4 wa = *(const float4*)(wr + c);
      float4 wb = *(const float4*)(wr + 192 + c);
      float4 wc = *(const float4*)(wr + 384 + c);
      float4 wd = *(const float4*)(wr + 576 + c);
      a0 += v0 * wa.x + v1 * wa.y + v2 * wa.z + v3 * wa.w;
      a1 += v0 * wb.x + v1 * wb.y + v2 * wb.z + v3 * wb.w;
      a2 += v0 * wc.x + v1 * wc.y + v2 * wc.z + v3 * wc.w;
      a3 += v0 * wd.x + v1 * wd.y + v2 * wd.z + v3 * wd.w;
    }
    h_lds[ni * 385 + oc0 + 0] = 0.5f * a0 * (1.f + erff(a0 * 0.70710678118f));
    h_lds[ni * 385 + oc0 + 1] = 0.5f * a1 * (1.f + erff(a1 * 0.70710678118f));
    h_lds[ni * 385 + oc0 + 2] = 0.5f * a2 * (1.f + erff(a2 * 0.70710678118f));
    h_lds[ni * 385 + oc0 + 3] = 0.5f * a3 * (1.f + erff(a3 * 0.70710678118f));
  }
  __syncthreads();

  // GEMM2: 192 outputs, 12 per group; fuse residual; write channel-major
  for (int ch = 0; ch < 3; ++ch) {
    const int oc0 = grp * 12 + ch * 4;
    float a0 = b2[oc0 + 0], a1 = b2[oc0 + 1], a2 = b2[oc0 + 2], a3 = b2[oc0 + 3];
    const float* wr = w2 + (size_t)oc0 * 384;
#pragma unroll 4
    for (int c = 0; c < 384; c += 4) {
      float v0 = h_lds[ni * 385 + c + 0];
      float v1 = h_lds[ni * 385 + c + 1];
      float v2 = h_lds[ni * 385 + c + 2];
      float v3 = h_lds[ni * 385 + c + 3];
      float4 wa = *(const float4*)(wr + c);
      float4 wb = *(const float4*)(wr + 384 + c);
      float4 wc = *(const float4*)(wr + 768 + c);
      float4 wd = *(const float4*)(wr + 1152 + c);
      a0 += v0 * wa.x + v1 * wa.y + v2 * wa.z + v3 * wa.w;
      a1 += v0 * wb.x + v1 * wb.y + v2 * wb.z + v3 * wb.w;
      a2 += v0 * wc.x + v1 * wc.y + v2 * wc.z + v3 * wc.w;
      a3 += v0 * wd.x + v1 * wd.y + v2 * wd.z + v3 * wd.w;
    }
    out[((size_t)b * 192 + oc0 + 0) * HW + n0 + ni] = a0 + o_lds[ni * 193 + oc0 + 0];
    out[((size_t)b * 192 + oc0 + 1) * HW + n0 + ni] = a1 + o_lds[ni * 193 + oc0 + 1];
    out[((size_t)b * 192 + oc0 + 2) * HW + n0 + ni] = a2 + o_lds[ni * 193 + oc0 + 2];
    out[((size_t)b * 192 + oc0 + 3) * HW + n0 + ni] = a3 + o_lds[ni * 193 + oc0 + 3];
  }
}

extern "C" void kernel_launch(void* const* d_in, const int* in_sizes, int n_in,
                              void* d_out, int out_size, void* d_ws, size_t ws_size,
                              hipStream_t stream) {
  const float* q = (const float*)d_in[0];
  const float* k = (const float*)d_in[1];
  const float* v = (const float*)d_in[2];
  const float* offset = (const float*)d_in[3];
  const float* wq = (const float*)d_in[4];
  const float* bq = (const float*)d_in[5];
  const float* wk = (const float*)d_in[6];
  const float* bk = (const float*)d_in[7];
  const float* wv = (const float*)d_in[8];
  const float* bv = (const float*)d_in[9];
  const float* w1 = (const float*)d_in[10];
  const float* b1 = (const float*)d_in[11];
  const float* w2 = (const float*)d_in[12];
  const float* b2 = (const float*)d_in[13];
  float* out = (float*)d_out;

  float* qp_t = (float*)d_ws;                       // 4*2304*192
  float* kvb = qp_t + (size_t)4 * HW * 192;         // 8*2304*384
  float* o_ws = kvb + (size_t)8 * HW * 384;         // 4*2304*192

  dim3 blk(256);
  proj_kernel<<<dim3(72, 4), blk, 0, stream>>>(q, wq, bq, qp_t, 192, 0);
  proj_kernel<<<dim3(72, 8), blk, 0, stream>>>(k, wk, bk, kvb, 384, 0);
  proj_kernel<<<dim3(72, 8), blk, 0, stream>>>(v, wv, bv, kvb, 384, 192);
  attn_kernel<<<dim3(216), blk, 0, stream>>>(qp_t, kvb, offset, o_ws);
  mlp_kernel<<<dim3(576), blk, 0, stream>>>(o_ws, w1, b1, w2, b2, out);
}

// Round 2
// 184.546 us; speedup vs baseline: 3.3033x; 3.3033x over previous
//
#include <hip/hip_runtime.h>

#define HW 2304
#define WID 48

typedef __attribute__((ext_vector_type(8))) short bf16x8;
typedef __attribute__((ext_vector_type(4))) float f32x4;

__device__ __forceinline__ unsigned pack_bf2(float lo, float hi) {
  unsigned a = __builtin_bit_cast(unsigned, lo);
  unsigned b = __builtin_bit_cast(unsigned, hi);
  a = (a + 0x7FFFu + ((a >> 16) & 1u)) >> 16;
  b = (b + 0x7FFFu + ((b >> 16) & 1u)) >> 16;
  return a | (b << 16);
}

// ---------------- Weight prep: fp32 [N][K] -> fragment-ordered bf16
// frag layout: [frag = nf*KS + ks][lane][8 bf16]; elem j of lane l holds
// w[nf*16 + (l&15)][ks*32 + (l>>4)*8 + j]  (same sigma as activation frags)
// regions (frag idx): wq 0..71, wk 72..143, wv 144..215, w1 216..359, w2 360..503
__global__ __launch_bounds__(256) void prep_w(
    const float* __restrict__ wq, const float* __restrict__ wk,
    const float* __restrict__ wv, const float* __restrict__ w1,
    const float* __restrict__ w2, unsigned* __restrict__ wf)
{
  int fid = blockIdx.x * 4 + (threadIdx.x >> 6);
  int l = threadIdx.x & 63;
  const float* src; int K; int base;
  if (fid < 72)       { src = wq; K = 192; base = 0; }
  else if (fid < 144) { src = wk; K = 192; base = 72; }
  else if (fid < 216) { src = wv; K = 192; base = 144; }
  else if (fid < 360) { src = w1; K = 192; base = 216; }
  else                { src = w2; K = 384; base = 360; }
  int local = fid - base;
  int KS = K / 32;
  int nf = local / KS, ks = local % KS;
  int row = nf * 16 + (l & 15);
  int c0 = ks * 32 + (l >> 4) * 8;
  const float* p = src + (size_t)row * K + c0;
  float4 v0 = *(const float4*)p;
  float4 v1 = *(const float4*)(p + 4);
  unsigned* dst = wf + ((size_t)fid * 64 + l) * 4;
  dst[0] = pack_bf2(v0.x, v0.y);
  dst[1] = pack_bf2(v0.z, v0.w);
  dst[2] = pack_bf2(v1.x, v1.y);
  dst[3] = pack_bf2(v1.z, v1.w);
}

// ---------------- Projection via MFMA: out[n][oc] = bias + sum_c in[c][n]*w[oc][c]
// grid.x = 36 pixel-tiles of 64, grid.y = 20 slabs (0-3 q, 4-11 k, 12-19 v)
__global__ __launch_bounds__(256) void proj_mfma(
    const float* __restrict__ q, const float* __restrict__ k, const float* __restrict__ v,
    const unsigned* __restrict__ wf,
    const float* __restrict__ bq, const float* __restrict__ bk, const float* __restrict__ bv,
    float* __restrict__ qp, float* __restrict__ kvb)
{
  __shared__ unsigned lds[64 * 100];  // [pix][cpair], stride 100 dw (16B-aligned rows)
  int slab = blockIdx.y;
  const float* in; const unsigned* wfr; const float* bias; float* outp; int ostride;
  if (slab < 4) {
    in = q + (size_t)slab * 192 * HW; wfr = wf; bias = bq;
    outp = qp + (size_t)slab * HW * 192; ostride = 192;
  } else if (slab < 12) {
    int c = slab - 4;
    in = k + (size_t)c * 192 * HW; wfr = wf + 72 * 256; bias = bk;
    outp = kvb + (size_t)c * HW * 384; ostride = 384;
  } else {
    int c = slab - 12;
    in = v + (size_t)c * 192 * HW; wfr = wf + 144 * 256; bias = bv;
    outp = kvb + (size_t)c * HW * 384 + 192; ostride = 384;
  }
  const int n0 = blockIdx.x * 64;
  const int t = threadIdx.x;
  const int w = t >> 6, l = t & 63;

  // stage activations: 64 pix x 96 cpairs (fp32 c-major -> bf16x2 pixel-major)
  {
    int pix = t & 63;
    int cp0 = t >> 6;
    const float* s0 = in + n0 + pix;
#pragma unroll
    for (int i = 0; i < 24; ++i) {
      int cp = cp0 * 24 + i;
      float lo = s0[(size_t)(2 * cp) * HW];
      float hi = s0[(size_t)(2 * cp + 1) * HW];
      lds[pix * 100 + cp] = pack_bf2(lo, hi);
    }
  }

  // hoist weight fragments (wave w owns output channels 48w..48w+47 = 3 nfrags)
  bf16x8 wfrag[6][3];
#pragma unroll
  for (int ks = 0; ks < 6; ++ks)
#pragma unroll
    for (int nfi = 0; nfi < 3; ++nfi) {
      int nf = w * 3 + nfi;
      wfrag[ks][nfi] = ((const bf16x8*)wfr)[(nf * 6 + ks) * 64 + l];
    }

  __syncthreads();

  f32x4 acc[3][4];
#pragma unroll
  for (int a = 0; a < 3; ++a)
#pragma unroll
    for (int m = 0; m < 4; ++m) acc[a][m] = (f32x4){0.f, 0.f, 0.f, 0.f};

#pragma unroll
  for (int ks = 0; ks < 6; ++ks) {
    bf16x8 af[4];
#pragma unroll
    for (int mf = 0; mf < 4; ++mf)
      af[mf] = *(const bf16x8*)&lds[(mf * 16 + (l & 15)) * 100 + ks * 16 + (l >> 4) * 4];
#pragma unroll
    for (int nfi = 0; nfi < 3; ++nfi)
#pragma unroll
      for (int mf = 0; mf < 4; ++mf)
        acc[nfi][mf] = __builtin_amdgcn_mfma_f32_16x16x32_bf16(af[mf], wfrag[ks][nfi], acc[nfi][mf], 0, 0, 0);
  }

  // epilogue: +bias, store out[pix][oc] (lanes 0-15 consecutive oc -> coalesced)
#pragma unroll
  for (int nfi = 0; nfi < 3; ++nfi) {
    int oc = (w * 3 + nfi) * 16 + (l & 15);
    float bs = bias[oc];
#pragma unroll
    for (int mf = 0; mf < 4; ++mf) {
      int pixb = n0 + mf * 16 + (l >> 4) * 4;
#pragma unroll
      for (int j = 0; j < 4; ++j)
        outp[(size_t)(pixb + j) * ostride + oc] = acc[nfi][mf][j] + bs;
    }
  }
}

// ---------------- Deformable attention: one thread per (b, n, head)
// qp: [B][HW][192], kv: [B*2][HW][384], offs: [B][2][216][HW], o_ws: [B][HW][192]
__global__ __launch_bounds__(256) void attn_kernel(
    const float* __restrict__ qp, const float* __restrict__ kv,
    const float* __restrict__ offs, float* __restrict__ o_ws)
{
  __shared__ float sc_lds[256 * 19];
  const int t = threadIdx.x;
  const int gid = blockIdx.x * 256 + t;
  const int n = gid % HW;
  const int rem = gid / HW;
  const int h = rem % 12;
  const int b = rem / 12;
  const int hh = n / WID, ww = n % WID;
  const int pk = h >> 1;
  float* sc = &sc_lds[t * 19];  // 18 scores [c*9+kk]

  float qv[16];
  {
    const float4* q4 = (const float4*)(qp + ((size_t)b * HW + n) * 192 + h * 16);
#pragma unroll
    for (int i = 0; i < 4; ++i) {
      float4 vv = q4[i];
      qv[4 * i + 0] = vv.x * 0.25f; qv[4 * i + 1] = vv.y * 0.25f;
      qv[4 * i + 2] = vv.z * 0.25f; qv[4 * i + 3] = vv.w * 0.25f;
    }
  }

  // ---- K phase
  for (int c = 0; c < 2; ++c) {
    const float* offb = offs + ((size_t)(b * 2 + c)) * 216 * HW + n;
    const float* kvb = kv + ((size_t)(b * 2 + c)) * HW * 384;
    for (int kk = 0; kk < 9; ++kk) {
      float oy = offb[(size_t)((pk * 9 + kk) * 2 + 0) * HW];
      float ox = offb[(size_t)((pk * 9 + kk) * 2 + 1) * HW];
      float py = (float)(hh - 1 + kk / 3) + oy;
      float px = (float)(ww - 1 + kk % 3) + ox;
      float y0f = floorf(py), x0f = floorf(px);
      int y0 = (int)y0f, x0 = (int)x0f;
      float wy1 = py - y0f, wx1 = px - x0f;
      float wy0 = 1.f - wy1, wx0 = 1.f - wx1;
      float s = 0.f;
#pragma unroll
      for (int cy = 0; cy < 2; ++cy) {
        int yi = y0 + cy;
        float wyv = cy ? wy1 : wy0;
#pragma unroll
        for (int cx = 0; cx < 2; ++cx) {
          int xi = x0 + cx;
          float wgt = wyv * (cx ? wx1 : wx0);
          if (!((unsigned)yi < 48u && (unsigned)xi < 48u)) wgt = 0.f;
          int yc = yi < 0 ? 0 : (yi > 47 ? 47 : yi);
          int xc = xi < 0 ? 0 : (xi > 47 ? 47 : xi);
          const float4* row = (const float4*)(kvb + (size_t)(yc * WID + xc) * 384 + h * 16);
          float d = 0.f;
#pragma unroll
          for (int i = 0; i < 4; ++i) {
            float4 vv = row[i];
            d += qv[4 * i + 0] * vv.x + qv[4 * i + 1] * vv.y + qv[4 * i + 2] * vv.z + qv[4 * i + 3] * vv.w;
          }
          s += wgt * d;
        }
      }
      sc[c * 9 + kk] = s;
    }
  }

  // ---- softmax over 18 taps
  {
    float m = -1e30f;
    for (int j = 0; j < 18; ++j) m = fmaxf(m, sc[j]);
    float sum = 0.f;
    for (int j = 0; j < 18; ++j) { float ev = __expf(sc[j] - m); sc[j] = ev; sum += ev; }
    float inv = 1.f / sum;
    for (int j = 0; j < 18; ++j) sc[j] *= inv;
  }

  // ---- V phase (offset group pk+6, v channels at +192)
  float acc[16];
#pragma unroll
  for (int i = 0; i < 16; ++i) acc[i] = 0.f;
  for (int c = 0; c < 2; ++c) {
    const float* offb = offs + ((size_t)(b * 2 + c)) * 216 * HW + n;
    const float* kvb = kv + ((size_t)(b * 2 + c)) * HW * 384;
    for (int kk = 0; kk < 9; ++kk) {
      float oy = offb[(size_t)(((pk + 6) * 9 + kk) * 2 + 0) * HW];
      float ox = offb[(size_t)(((pk + 6) * 9 + kk) * 2 + 1) * HW];
      float py = (float)(hh - 1 + kk / 3) + oy;
      float px = (float)(ww - 1 + kk % 3) + ox;
      float y0f = floorf(py), x0f = floorf(px);
      int y0 = (int)y0f, x0 = (int)x0f;
      float wy1 = py - y0f, wx1 = px - x0f;
      float wy0 = 1.f - wy1, wx0 = 1.f - wx1;
      float aw = sc[c * 9 + kk];
#pragma unroll
      for (int cy = 0; cy < 2; ++cy) {
        int yi = y0 + cy;
        float wyv = cy ? wy1 : wy0;
#pragma unroll
        for (int cx = 0; cx < 2; ++cx) {
          int xi = x0 + cx;
          float wgt = wyv * (cx ? wx1 : wx0);
          if (!((unsigned)yi < 48u && (unsigned)xi < 48u)) wgt = 0.f;
          int yc = yi < 0 ? 0 : (yi > 47 ? 47 : yi);
          int xc = xi < 0 ? 0 : (xi > 47 ? 47 : xi);
          const float4* row = (const float4*)(kvb + (size_t)(yc * WID + xc) * 384 + 192 + h * 16);
          float cw = wgt * aw;
#pragma unroll
          for (int i = 0; i < 4; ++i) {
            float4 vv = row[i];
            acc[4 * i + 0] += cw * vv.x; acc[4 * i + 1] += cw * vv.y;
            acc[4 * i + 2] += cw * vv.z; acc[4 * i + 3] += cw * vv.w;
          }
        }
      }
    }
  }

  float* orow = o_ws + ((size_t)b * HW + n) * 192 + h * 16;
#pragma unroll
  for (int i = 0; i < 4; ++i) {
    float4 r; r.x = acc[4 * i]; r.y = acc[4 * i + 1]; r.z = acc[4 * i + 2]; r.w = acc[4 * i + 3];
    *(float4*)(orow + 4 * i) = r;
  }
}

// ---------------- MLP via MFMA: out[b][oc][n] = o + w2 @ gelu(w1 @ o + b1) + b2
// one block per 16-pixel tile; 4 waves split N
__global__ __launch_bounds__(256) void mlp_mfma(
    const float* __restrict__ o_ws, const unsigned* __restrict__ wf,
    const float* __restrict__ b1, const float* __restrict__ b2,
    float* __restrict__ out)
{
  __shared__ unsigned ldsO[16 * 100];  // o tile  [pix][cpair<96]
  __shared__ unsigned ldsH[16 * 196];  // h tile  [pix][hcpair<192]
  const unsigned* w1f = wf + 216 * 256;
  const unsigned* w2f = wf + 360 * 256;
  const int blk = blockIdx.x;
  const int b = blk / 144;
  const int n0 = (blk % 144) * 16;
  const int t = threadIdx.x;
  const int w = t >> 6, l = t & 63;

  for (int i = t; i < 16 * 96; i += 256) {
    int pix = i / 96, cp = i % 96;
    const float2 s = *(const float2*)(o_ws + ((size_t)(b * HW) + n0 + pix) * 192 + 2 * cp);
    ldsO[pix * 100 + cp] = pack_bf2(s.x, s.y);
  }
  __syncthreads();

  // GEMM1: N=384, wave w owns h-channels 96w..96w+95 (6 nfrags); K=192
  f32x4 acc1[6];
#pragma unroll
  for (int a = 0; a < 6; ++a) acc1[a] = (f32x4){0.f, 0.f, 0.f, 0.f};
#pragma unroll
  for (int ks = 0; ks < 6; ++ks) {
    bf16x8 af = *(const bf16x8*)&ldsO[(l & 15) * 100 + ks * 16 + (l >> 4) * 4];
#pragma unroll
    for (int nfi = 0; nfi < 6; ++nfi) {
      int nf = w * 6 + nfi;
      bf16x8 bfr = ((const bf16x8*)w1f)[(nf * 6 + ks) * 64 + l];
      acc1[nfi] = __builtin_amdgcn_mfma_f32_16x16x32_bf16(af, bfr, acc1[nfi], 0, 0, 0);
    }
  }

  // bias + exact GELU -> bf16 into ldsH
  {
    unsigned short* ldsHu = (unsigned short*)ldsH;
#pragma unroll
    for (int nfi = 0; nfi < 6; ++nfi) {
      int hc = (w * 6 + nfi) * 16 + (l & 15);
      float bs = b1[hc];
#pragma unroll
      for (int j = 0; j < 4; ++j) {
        int pix = (l >> 4) * 4 + j;
        float x = acc1[nfi][j] + bs;
        float g = 0.5f * x * (1.f + erff(x * 0.70710678118654752f));
        unsigned gb = __builtin_bit_cast(unsigned, g);
        gb = (gb + 0x7FFFu + ((gb >> 16) & 1u)) >> 16;
        ldsHu[pix * 392 + hc] = (unsigned short)gb;
      }
    }
  }
  __syncthreads();

  // GEMM2: N=192, wave w owns oc 48w..48w+47 (3 nfrags); K=384
  f32x4 acc2[3];
#pragma unroll
  for (int a = 0; a < 3; ++a) acc2[a] = (f32x4){0.f, 0.f, 0.f, 0.f};
#pragma unroll
  for (int ks = 0; ks < 12; ++ks) {
    bf16x8 af = *(const bf16x8*)&ldsH[(l & 15) * 196 + ks * 16 + (l >> 4) * 4];
#pragma unroll
    for (int nfi = 0; nfi < 3; ++nfi) {
      int nf = w * 3 + nfi;
      bf16x8 bfr = ((const bf16x8*)w2f)[(nf * 12 + ks) * 64 + l];
      acc2[nfi] = __builtin_amdgcn_mfma_f32_16x16x32_bf16(af, bfr, acc2[nfi], 0, 0, 0);
    }
  }

  // epilogue: + b2 + fp32 residual from o_ws, store channel-major
#pragma unroll
  for (int nfi = 0; nfi < 3; ++nfi) {
    int oc = (w * 3 + nfi) * 16 + (l & 15);
    float bs = b2[oc];
#pragma unroll
    for (int j = 0; j < 4; ++j) {
      int pix = (l >> 4) * 4 + j;
      float res = o_ws[((size_t)(b * HW) + n0 + pix) * 192 + oc];
      out[((size_t)b * 192 + oc) * HW + n0 + pix] = acc2[nfi][j] + bs + res;
    }
  }
}

extern "C" void kernel_launch(void* const* d_in, const int* in_sizes, int n_in,
                              void* d_out, int out_size, void* d_ws, size_t ws_size,
                              hipStream_t stream) {
  const float* q = (const float*)d_in[0];
  const float* k = (const float*)d_in[1];
  const float* v = (const float*)d_in[2];
  const float* offset = (const float*)d_in[3];
  const float* wq = (const float*)d_in[4];
  const float* bq = (const float*)d_in[5];
  const float* wk = (const float*)d_in[6];
  const float* bk = (const float*)d_in[7];
  const float* wv = (const float*)d_in[8];
  const float* bv = (const float*)d_in[9];
  const float* w1 = (const float*)d_in[10];
  const float* b1 = (const float*)d_in[11];
  const float* w2 = (const float*)d_in[12];
  const float* b2 = (const float*)d_in[13];
  float* out = (float*)d_out;

  float* qp_t = (float*)d_ws;                        // 4*2304*192 f
  float* kvb = qp_t + (size_t)4 * HW * 192;          // 8*2304*384 f
  float* o_ws = kvb + (size_t)8 * HW * 384;          // 4*2304*192 f
  unsigned* wfb = (unsigned*)(o_ws + (size_t)4 * HW * 192);  // 504 frags * 256 u32

  dim3 blk(256);
  prep_w<<<dim3(126), blk, 0, stream>>>(wq, wk, wv, w1, w2, wfb);
  proj_mfma<<<dim3(36, 20), blk, 0, stream>>>(q, k, v, wfb, bq, bk, bv, qp_t, kvb);
  attn_kernel<<<dim3(432), blk, 0, stream>>>(qp_t, kvb, offset, o_ws);
  mlp_mfma<<<dim3(576), blk, 0, stream>>>(o_ws, wfb, b1, b2, out);
}

// Round 3
// 117.937 us; speedup vs baseline: 5.1689x; 1.5648x over previous
//
#include <hip/hip_runtime.h>

#define HW 2304
#define WID 48

typedef __attribute__((ext_vector_type(8))) short bf16x8;
typedef __attribute__((ext_vector_type(4))) float f32x4;

__device__ __forceinline__ unsigned pack_bf2(float lo, float hi) {
  unsigned a = __builtin_bit_cast(unsigned, lo);
  unsigned b = __builtin_bit_cast(unsigned, hi);
  a = (a + 0x7FFFu + ((a >> 16) & 1u)) >> 16;
  b = (b + 0x7FFFu + ((b >> 16) & 1u)) >> 16;
  return a | (b << 16);
}

// ---------------- Weight prep: fp32 [N][K] -> fragment-ordered bf16
// frag layout: [frag = nf*KS + ks][lane][8 bf16]; elem j of lane l holds
// w[nf*16 + (l&15)][ks*32 + (l>>4)*8 + j]  (same sigma as activation frags)
// regions (frag idx): wq 0..71, wk 72..143, wv 144..215, w1 216..359, w2 360..503
__global__ __launch_bounds__(256) void prep_w(
    const float* __restrict__ wq, const float* __restrict__ wk,
    const float* __restrict__ wv, const float* __restrict__ w1,
    const float* __restrict__ w2, unsigned* __restrict__ wf)
{
  int fid = blockIdx.x * 4 + (threadIdx.x >> 6);
  int l = threadIdx.x & 63;
  const float* src; int K; int base;
  if (fid < 72)       { src = wq; K = 192; base = 0; }
  else if (fid < 144) { src = wk; K = 192; base = 72; }
  else if (fid < 216) { src = wv; K = 192; base = 144; }
  else if (fid < 360) { src = w1; K = 192; base = 216; }
  else                { src = w2; K = 384; base = 360; }
  int local = fid - base;
  int KS = K / 32;
  int nf = local / KS, ks = local % KS;
  int row = nf * 16 + (l & 15);
  int c0 = ks * 32 + (l >> 4) * 8;
  const float* p = src + (size_t)row * K + c0;
  float4 v0 = *(const float4*)p;
  float4 v1 = *(const float4*)(p + 4);
  unsigned* dst = wf + ((size_t)fid * 64 + l) * 4;
  dst[0] = pack_bf2(v0.x, v0.y);
  dst[1] = pack_bf2(v0.z, v0.w);
  dst[2] = pack_bf2(v1.x, v1.y);
  dst[3] = pack_bf2(v1.z, v1.w);
}

// ---------------- Projection via MFMA: out[n][oc] = bias + sum_c in[c][n]*w[oc][c]
// grid.x = 36 pixel-tiles of 64, grid.y = 20 slabs (0-3 q, 4-11 k, 12-19 v)
__global__ __launch_bounds__(256) void proj_mfma(
    const float* __restrict__ q, const float* __restrict__ k, const float* __restrict__ v,
    const unsigned* __restrict__ wf,
    const float* __restrict__ bq, const float* __restrict__ bk, const float* __restrict__ bv,
    float* __restrict__ qp, float* __restrict__ kvb)
{
  __shared__ unsigned lds[64 * 100];  // [pix][cpair], stride 100 dw (16B-aligned rows)
  int slab = blockIdx.y;
  const float* in; const unsigned* wfr; const float* bias; float* outp; int ostride;
  if (slab < 4) {
    in = q + (size_t)slab * 192 * HW; wfr = wf; bias = bq;
    outp = qp + (size_t)slab * HW * 192; ostride = 192;
  } else if (slab < 12) {
    int c = slab - 4;
    in = k + (size_t)c * 192 * HW; wfr = wf + 72 * 256; bias = bk;
    outp = kvb + (size_t)c * HW * 384; ostride = 384;
  } else {
    int c = slab - 12;
    in = v + (size_t)c * 192 * HW; wfr = wf + 144 * 256; bias = bv;
    outp = kvb + (size_t)c * HW * 384 + 192; ostride = 384;
  }
  const int n0 = blockIdx.x * 64;
  const int t = threadIdx.x;
  const int w = t >> 6, l = t & 63;

  // stage activations: 64 pix x 96 cpairs (fp32 c-major -> bf16x2 pixel-major)
  {
    int pix = t & 63;
    int cp0 = t >> 6;
    const float* s0 = in + n0 + pix;
#pragma unroll
    for (int i = 0; i < 24; ++i) {
      int cp = cp0 * 24 + i;
      float lo = s0[(size_t)(2 * cp) * HW];
      float hi = s0[(size_t)(2 * cp + 1) * HW];
      lds[pix * 100 + cp] = pack_bf2(lo, hi);
    }
  }

  // hoist weight fragments (wave w owns output channels 48w..48w+47 = 3 nfrags)
  bf16x8 wfrag[6][3];
#pragma unroll
  for (int ks = 0; ks < 6; ++ks)
#pragma unroll
    for (int nfi = 0; nfi < 3; ++nfi) {
      int nf = w * 3 + nfi;
      wfrag[ks][nfi] = ((const bf16x8*)wfr)[(nf * 6 + ks) * 64 + l];
    }

  __syncthreads();

  f32x4 acc[3][4];
#pragma unroll
  for (int a = 0; a < 3; ++a)
#pragma unroll
    for (int m = 0; m < 4; ++m) acc[a][m] = (f32x4){0.f, 0.f, 0.f, 0.f};

#pragma unroll
  for (int ks = 0; ks < 6; ++ks) {
    bf16x8 af[4];
#pragma unroll
    for (int mf = 0; mf < 4; ++mf)
      af[mf] = *(const bf16x8*)&lds[(mf * 16 + (l & 15)) * 100 + ks * 16 + (l >> 4) * 4];
#pragma unroll
    for (int nfi = 0; nfi < 3; ++nfi)
#pragma unroll
      for (int mf = 0; mf < 4; ++mf)
        acc[nfi][mf] = __builtin_amdgcn_mfma_f32_16x16x32_bf16(af[mf], wfrag[ks][nfi], acc[nfi][mf], 0, 0, 0);
  }

  // epilogue: +bias, store out[pix][oc] (lanes 0-15 consecutive oc -> coalesced)
#pragma unroll
  for (int nfi = 0; nfi < 3; ++nfi) {
    int oc = (w * 3 + nfi) * 16 + (l & 15);
    float bs = bias[oc];
#pragma unroll
    for (int mf = 0; mf < 4; ++mf) {
      int pixb = n0 + mf * 16 + (l >> 4) * 4;
#pragma unroll
      for (int j = 0; j < 4; ++j)
        outp[(size_t)(pixb + j) * ostride + oc] = acc[nfi][mf][j] + bs;
    }
  }
}

// ---------------- Deformable attention: 4 lanes per (b, n, head) — one float4 of
// the 16-dim head each. Scores in registers; per-tap reduce via shfl_xor(1,2).
// qp: [B][HW][192], kv: [B*2][HW][384], offs: [B][2][216][HW], o_ws: [B][HW][192]
__global__ __launch_bounds__(256) void attn_kernel(
    const float* __restrict__ qp, const float* __restrict__ kv,
    const float* __restrict__ offs, float* __restrict__ o_ws)
{
  const int t = threadIdx.x;
  const int gid = blockIdx.x * 256 + t;
  const int sub = gid & 3;
  const int idx = gid >> 2;          // (b, h, n) with n fastest
  const int n = idx % HW;
  const int rem = idx / HW;
  const int h = rem % 12;
  const int b = rem / 12;
  const int hh = n / WID, ww = n % WID;
  const int pk = h >> 1;

  float4 qv;
  {
    float4 vv = *(const float4*)(qp + ((size_t)b * HW + n) * 192 + h * 16 + sub * 4);
    qv.x = vv.x * 0.25f; qv.y = vv.y * 0.25f; qv.z = vv.z * 0.25f; qv.w = vv.w * 0.25f;
  }

  float sc[18];

  // ---- K phase
#pragma unroll
  for (int c = 0; c < 2; ++c) {
    const float* offb = offs + ((size_t)(b * 2 + c)) * 216 * HW + n;
    const float* kvb = kv + ((size_t)(b * 2 + c)) * HW * 384;
#pragma unroll
    for (int kk = 0; kk < 9; ++kk) {
      float oy = offb[(size_t)((pk * 9 + kk) * 2 + 0) * HW];
      float ox = offb[(size_t)((pk * 9 + kk) * 2 + 1) * HW];
      float py = (float)(hh - 1 + kk / 3) + oy;
      float px = (float)(ww - 1 + kk % 3) + ox;
      float y0f = floorf(py), x0f = floorf(px);
      int y0 = (int)y0f, x0 = (int)x0f;
      float wy1 = py - y0f, wx1 = px - x0f;
      float wy0 = 1.f - wy1, wx0 = 1.f - wx1;
      float s = 0.f;
#pragma unroll
      for (int cy = 0; cy < 2; ++cy) {
        int yi = y0 + cy;
        float wyv = cy ? wy1 : wy0;
#pragma unroll
        for (int cx = 0; cx < 2; ++cx) {
          int xi = x0 + cx;
          float wgt = wyv * (cx ? wx1 : wx0);
          if (!((unsigned)yi < 48u && (unsigned)xi < 48u)) wgt = 0.f;
          int yc = yi < 0 ? 0 : (yi > 47 ? 47 : yi);
          int xc = xi < 0 ? 0 : (xi > 47 ? 47 : xi);
          float4 vv = *(const float4*)(kvb + (size_t)(yc * WID + xc) * 384 + h * 16 + sub * 4);
          s += wgt * (qv.x * vv.x + qv.y * vv.y + qv.z * vv.z + qv.w * vv.w);
        }
      }
      // complete the 16-dim dot across the 4 sub-lanes
      s += __shfl_xor(s, 1, 64);
      s += __shfl_xor(s, 2, 64);
      sc[c * 9 + kk] = s;
    }
  }

  // ---- softmax over 18 taps (in registers, redundant per sub-lane)
  {
    float m = -1e30f;
#pragma unroll
    for (int j = 0; j < 18; ++j) m = fmaxf(m, sc[j]);
    float sum = 0.f;
#pragma unroll
    for (int j = 0; j < 18; ++j) { float ev = __expf(sc[j] - m); sc[j] = ev; sum += ev; }
    float inv = 1.f / sum;
#pragma unroll
    for (int j = 0; j < 18; ++j) sc[j] *= inv;
  }

  // ---- V phase (offset group pk+6, v channels at +192)
  float ax = 0.f, ay = 0.f, az = 0.f, aw = 0.f;
#pragma unroll
  for (int c = 0; c < 2; ++c) {
    const float* offb = offs + ((size_t)(b * 2 + c)) * 216 * HW + n;
    const float* kvb = kv + ((size_t)(b * 2 + c)) * HW * 384;
#pragma unroll
    for (int kk = 0; kk < 9; ++kk) {
      float oy = offb[(size_t)(((pk + 6) * 9 + kk) * 2 + 0) * HW];
      float ox = offb[(size_t)(((pk + 6) * 9 + kk) * 2 + 1) * HW];
      float py = (float)(hh - 1 + kk / 3) + oy;
      float px = (float)(ww - 1 + kk % 3) + ox;
      float y0f = floorf(py), x0f = floorf(px);
      int y0 = (int)y0f, x0 = (int)x0f;
      float wy1 = py - y0f, wx1 = px - x0f;
      float wy0 = 1.f - wy1, wx0 = 1.f - wx1;
      float at = sc[c * 9 + kk];
#pragma unroll
      for (int cy = 0; cy < 2; ++cy) {
        int yi = y0 + cy;
        float wyv = cy ? wy1 : wy0;
#pragma unroll
        for (int cx = 0; cx < 2; ++cx) {
          int xi = x0 + cx;
          float wgt = wyv * (cx ? wx1 : wx0);
          if (!((unsigned)yi < 48u && (unsigned)xi < 48u)) wgt = 0.f;
          int yc = yi < 0 ? 0 : (yi > 47 ? 47 : yi);
          int xc = xi < 0 ? 0 : (xi > 47 ? 47 : xi);
          float4 vv = *(const float4*)(kvb + (size_t)(yc * WID + xc) * 384 + 192 + h * 16 + sub * 4);
          float cw = wgt * at;
          ax += cw * vv.x; ay += cw * vv.y; az += cw * vv.z; aw += cw * vv.w;
        }
      }
    }
  }

  float4 r; r.x = ax; r.y = ay; r.z = az; r.w = aw;
  *(float4*)(o_ws + ((size_t)b * HW + n) * 192 + h * 16 + sub * 4) = r;
}

// ---------------- MLP via MFMA: out[b][oc][n] = o + w2 @ gelu(w1 @ o + b1) + b2
// one block per 16-pixel tile; 4 waves split N
__global__ __launch_bounds__(256) void mlp_mfma(
    const float* __restrict__ o_ws, const unsigned* __restrict__ wf,
    const float* __restrict__ b1, const float* __restrict__ b2,
    float* __restrict__ out)
{
  __shared__ unsigned ldsO[16 * 100];  // o tile  [pix][cpair<96]
  __shared__ unsigned ldsH[16 * 196];  // h tile  [pix][hcpair<192]
  const unsigned* w1f = wf + 216 * 256;
  const unsigned* w2f = wf + 360 * 256;
  const int blk = blockIdx.x;
  const int b = blk / 144;
  const int n0 = (blk % 144) * 16;
  const int t = threadIdx.x;
  const int w = t >> 6, l = t & 63;

  for (int i = t; i < 16 * 96; i += 256) {
    int pix = i / 96, cp = i % 96;
    const float2 s = *(const float2*)(o_ws + ((size_t)(b * HW) + n0 + pix) * 192 + 2 * cp);
    ldsO[pix * 100 + cp] = pack_bf2(s.x, s.y);
  }
  __syncthreads();

  // GEMM1: N=384, wave w owns h-channels 96w..96w+95 (6 nfrags); K=192
  f32x4 acc1[6];
#pragma unroll
  for (int a = 0; a < 6; ++a) acc1[a] = (f32x4){0.f, 0.f, 0.f, 0.f};
#pragma unroll
  for (int ks = 0; ks < 6; ++ks) {
    bf16x8 af = *(const bf16x8*)&ldsO[(l & 15) * 100 + ks * 16 + (l >> 4) * 4];
#pragma unroll
    for (int nfi = 0; nfi < 6; ++nfi) {
      int nf = w * 6 + nfi;
      bf16x8 bfr = ((const bf16x8*)w1f)[(nf * 6 + ks) * 64 + l];
      acc1[nfi] = __builtin_amdgcn_mfma_f32_16x16x32_bf16(af, bfr, acc1[nfi], 0, 0, 0);
    }
  }

  // bias + exact GELU -> bf16 into ldsH
  {
    unsigned short* ldsHu = (unsigned short*)ldsH;
#pragma unroll
    for (int nfi = 0; nfi < 6; ++nfi) {
      int hc = (w * 6 + nfi) * 16 + (l & 15);
      float bs = b1[hc];
#pragma unroll
      for (int j = 0; j < 4; ++j) {
        int pix = (l >> 4) * 4 + j;
        float x = acc1[nfi][j] + bs;
        float g = 0.5f * x * (1.f + erff(x * 0.70710678118654752f));
        unsigned gb = __builtin_bit_cast(unsigned, g);
        gb = (gb + 0x7FFFu + ((gb >> 16) & 1u)) >> 16;
        ldsHu[pix * 392 + hc] = (unsigned short)gb;
      }
    }
  }
  __syncthreads();

  // GEMM2: N=192, wave w owns oc 48w..48w+47 (3 nfrags); K=384
  f32x4 acc2[3];
#pragma unroll
  for (int a = 0; a < 3; ++a) acc2[a] = (f32x4){0.f, 0.f, 0.f, 0.f};
#pragma unroll
  for (int ks = 0; ks < 12; ++ks) {
    bf16x8 af = *(const bf16x8*)&ldsH[(l & 15) * 196 + ks * 16 + (l >> 4) * 4];
#pragma unroll
    for (int nfi = 0; nfi < 3; ++nfi) {
      int nf = w * 3 + nfi;
      bf16x8 bfr = ((const bf16x8*)w2f)[(nf * 12 + ks) * 64 + l];
      acc2[nfi] = __builtin_amdgcn_mfma_f32_16x16x32_bf16(af, bfr, acc2[nfi], 0, 0, 0);
    }
  }

  // epilogue: + b2 + fp32 residual from o_ws, store channel-major
#pragma unroll
  for (int nfi = 0; nfi < 3; ++nfi) {
    int oc = (w * 3 + nfi) * 16 + (l & 15);
    float bs = b2[oc];
#pragma unroll
    for (int j = 0; j < 4; ++j) {
      int pix = (l >> 4) * 4 + j;
      float res = o_ws[((size_t)(b * HW) + n0 + pix) * 192 + oc];
      out[((size_t)b * 192 + oc) * HW + n0 + pix] = acc2[nfi][j] + bs + res;
    }
  }
}

extern "C" void kernel_launch(void* const* d_in, const int* in_sizes, int n_in,
                              void* d_out, int out_size, void* d_ws, size_t ws_size,
                              hipStream_t stream) {
  const float* q = (const float*)d_in[0];
  const float* k = (const float*)d_in[1];
  const float* v = (const float*)d_in[2];
  const float* offset = (const float*)d_in[3];
  const float* wq = (const float*)d_in[4];
  const float* bq = (const float*)d_in[5];
  const float* wk = (const float*)d_in[6];
  const float* bk = (const float*)d_in[7];
  const float* wv = (const float*)d_in[8];
  const float* bv = (const float*)d_in[9];
  const float* w1 = (const float*)d_in[10];
  const float* b1 = (const float*)d_in[11];
  const float* w2 = (const float*)d_in[12];
  const float* b2 = (const float*)d_in[13];
  float* out = (float*)d_out;

  float* qp_t = (float*)d_ws;                        // 4*2304*192 f
  float* kvb = qp_t + (size_t)4 * HW * 192;          // 8*2304*384 f
  float* o_ws = kvb + (size_t)8 * HW * 384;          // 4*2304*192 f
  unsigned* wfb = (unsigned*)(o_ws + (size_t)4 * HW * 192);  // 504 frags * 256 u32

  dim3 blk(256);
  prep_w<<<dim3(126), blk, 0, stream>>>(wq, wk, wv, w1, w2, wfb);
  proj_mfma<<<dim3(36, 20), blk, 0, stream>>>(q, k, v, wfb, bq, bk, bv, qp_t, kvb);
  attn_kernel<<<dim3(1728), blk, 0, stream>>>(qp_t, kvb, offset, o_ws);
  mlp_mfma<<<dim3(576), blk, 0, stream>>>(o_ws, wfb, b1, b2, out);
}

// Round 4
// 91.174 us; speedup vs baseline: 6.6862x; 1.2935x over previous
//
#include <hip/hip_runtime.h>

#define HW 2304
#define WID 48

typedef __attribute__((ext_vector_type(8))) short bf16x8;
typedef __attribute__((ext_vector_type(4))) float f32x4;

__device__ __forceinline__ unsigned pack_bf2(float lo, float hi) {
  unsigned a = __builtin_bit_cast(unsigned, lo);
  unsigned b = __builtin_bit_cast(unsigned, hi);
  a = (a + 0x7FFFu + ((a >> 16) & 1u)) >> 16;
  b = (b + 0x7FFFu + ((b >> 16) & 1u)) >> 16;
  return a | (b << 16);
}
__device__ __forceinline__ unsigned short bf16_of(float x) {
  unsigned u = __builtin_bit_cast(unsigned, x);
  u = (u + 0x7FFFu + ((u >> 16) & 1u)) >> 16;
  return (unsigned short)u;
}
__device__ __forceinline__ float lo_bf(unsigned u) {
  return __builtin_bit_cast(float, u << 16);
}
__device__ __forceinline__ float hi_bf(unsigned u) {
  return __builtin_bit_cast(float, u & 0xFFFF0000u);
}

// ---------------- Weight prep: fp32 [N][K] -> fragment-ordered bf16
__global__ __launch_bounds__(256) void prep_w(
    const float* __restrict__ wq, const float* __restrict__ wk,
    const float* __restrict__ wv, const float* __restrict__ w1,
    const float* __restrict__ w2, unsigned* __restrict__ wf)
{
  int fid = blockIdx.x * 4 + (threadIdx.x >> 6);
  int l = threadIdx.x & 63;
  const float* src; int K; int base;
  if (fid < 72)       { src = wq; K = 192; base = 0; }
  else if (fid < 144) { src = wk; K = 192; base = 72; }
  else if (fid < 216) { src = wv; K = 192; base = 144; }
  else if (fid < 360) { src = w1; K = 192; base = 216; }
  else                { src = w2; K = 384; base = 360; }
  int local = fid - base;
  int KS = K / 32;
  int nf = local / KS, ks = local % KS;
  int row = nf * 16 + (l & 15);
  int c0 = ks * 32 + (l >> 4) * 8;
  const float* p = src + (size_t)row * K + c0;
  float4 v0 = *(const float4*)p;
  float4 v1 = *(const float4*)(p + 4);
  unsigned* dst = wf + ((size_t)fid * 64 + l) * 4;
  dst[0] = pack_bf2(v0.x, v0.y);
  dst[1] = pack_bf2(v0.z, v0.w);
  dst[2] = pack_bf2(v1.x, v1.y);
  dst[3] = pack_bf2(v1.z, v1.w);
}

// ---------------- Projection via MFMA. q slab -> fp32 qp [B][HW][192];
// k/v slabs -> bf16 kvh [B*2][HW][384] (k at 0, v at +192)
__global__ __launch_bounds__(256) void proj_mfma(
    const float* __restrict__ q, const float* __restrict__ k, const float* __restrict__ v,
    const unsigned* __restrict__ wf,
    const float* __restrict__ bq, const float* __restrict__ bk, const float* __restrict__ bv,
    float* __restrict__ qp, unsigned short* __restrict__ kvh)
{
  __shared__ unsigned lds[64 * 100];
  int slab = blockIdx.y;
  const float* in; const unsigned* wfr; const float* bias;
  float* outf = nullptr; unsigned short* outh = nullptr;
  if (slab < 4) {
    in = q + (size_t)slab * 192 * HW; wfr = wf; bias = bq;
    outf = qp + (size_t)slab * HW * 192;
  } else if (slab < 12) {
    int c = slab - 4;
    in = k + (size_t)c * 192 * HW; wfr = wf + 72 * 256; bias = bk;
    outh = kvh + (size_t)c * HW * 384;
  } else {
    int c = slab - 12;
    in = v + (size_t)c * 192 * HW; wfr = wf + 144 * 256; bias = bv;
    outh = kvh + (size_t)c * HW * 384 + 192;
  }
  const int n0 = blockIdx.x * 64;
  const int t = threadIdx.x;
  const int w = t >> 6, l = t & 63;

  {
    int pix = t & 63;
    int cp0 = t >> 6;
    const float* s0 = in + n0 + pix;
#pragma unroll
    for (int i = 0; i < 24; ++i) {
      int cp = cp0 * 24 + i;
      float lo = s0[(size_t)(2 * cp) * HW];
      float hi = s0[(size_t)(2 * cp + 1) * HW];
      lds[pix * 100 + cp] = pack_bf2(lo, hi);
    }
  }

  bf16x8 wfrag[6][3];
#pragma unroll
  for (int ks = 0; ks < 6; ++ks)
#pragma unroll
    for (int nfi = 0; nfi < 3; ++nfi) {
      int nf = w * 3 + nfi;
      wfrag[ks][nfi] = ((const bf16x8*)wfr)[(nf * 6 + ks) * 64 + l];
    }

  __syncthreads();

  f32x4 acc[3][4];
#pragma unroll
  for (int a = 0; a < 3; ++a)
#pragma unroll
    for (int m = 0; m < 4; ++m) acc[a][m] = (f32x4){0.f, 0.f, 0.f, 0.f};

#pragma unroll
  for (int ks = 0; ks < 6; ++ks) {
    bf16x8 af[4];
#pragma unroll
    for (int mf = 0; mf < 4; ++mf)
      af[mf] = *(const bf16x8*)&lds[(mf * 16 + (l & 15)) * 100 + ks * 16 + (l >> 4) * 4];
#pragma unroll
    for (int nfi = 0; nfi < 3; ++nfi)
#pragma unroll
      for (int mf = 0; mf < 4; ++mf)
        acc[nfi][mf] = __builtin_amdgcn_mfma_f32_16x16x32_bf16(af[mf], wfrag[ks][nfi], acc[nfi][mf], 0, 0, 0);
  }

#pragma unroll
  for (int nfi = 0; nfi < 3; ++nfi) {
    int oc = (w * 3 + nfi) * 16 + (l & 15);
    float bs = bias[oc];
    if (outf) {
#pragma unroll
      for (int mf = 0; mf < 4; ++mf) {
        int pixb = n0 + mf * 16 + (l >> 4) * 4;
#pragma unroll
        for (int j = 0; j < 4; ++j)
          outf[(size_t)(pixb + j) * 192 + oc] = acc[nfi][mf][j] + bs;
      }
    } else {
#pragma unroll
      for (int mf = 0; mf < 4; ++mf) {
        int pixb = n0 + mf * 16 + (l >> 4) * 4;
#pragma unroll
        for (int j = 0; j < 4; ++j)
          outh[(size_t)(pixb + j) * 384 + oc] = bf16_of(acc[nfi][mf][j] + bs);
      }
    }
  }
}

// ---------------- Deformable attention: 4 lanes per (b, n, head); bf16 KV.
// XCD-chunked swizzle: blockIdx%8 -> (b, pixel-half) so each XCD's L2 holds
// one batch-half's KV slab; pos = blockIdx/8 -> (h, 64-pixel tile).
// qp: [B][HW][192] f32, kvh: [B*2][HW][384] bf16, offs: [B][2][216][HW] f32
__global__ __launch_bounds__(256) void attn_kernel(
    const float* __restrict__ qp, const unsigned short* __restrict__ kvh,
    const float* __restrict__ offs, float* __restrict__ o_ws)
{
  const int t = threadIdx.x;
  const int g = blockIdx.x & 7;          // XCD group: (b, half)
  const int pos = blockIdx.x >> 3;       // 0..215: (h, tile)
  const int b = g >> 1;
  const int half = g & 1;
  const int h = pos / 18;
  const int tile = pos % 18;
  const int n = half * 1152 + tile * 64 + (t >> 2);
  const int sub = t & 3;
  const int hh = n / WID, ww = n % WID;
  const int pk = h >> 1;

  float4 qv;
  {
    float4 vv = *(const float4*)(qp + ((size_t)b * HW + n) * 192 + h * 16 + sub * 4);
    qv.x = vv.x * 0.25f; qv.y = vv.y * 0.25f; qv.z = vv.z * 0.25f; qv.w = vv.w * 0.25f;
  }

  float sc[18];

  // ---- K phase
#pragma unroll
  for (int c = 0; c < 2; ++c) {
    const float* offb = offs + ((size_t)(b * 2 + c)) * 216 * HW + n;
    const unsigned short* kvb = kvh + ((size_t)(b * 2 + c)) * HW * 384;
#pragma unroll
    for (int kk = 0; kk < 9; ++kk) {
      float oy = offb[(size_t)((pk * 9 + kk) * 2 + 0) * HW];
      float ox = offb[(size_t)((pk * 9 + kk) * 2 + 1) * HW];
      float py = (float)(hh - 1 + kk / 3) + oy;
      float px = (float)(ww - 1 + kk % 3) + ox;
      float y0f = floorf(py), x0f = floorf(px);
      int y0 = (int)y0f, x0 = (int)x0f;
      float wy1 = py - y0f, wx1 = px - x0f;
      float wy0 = 1.f - wy1, wx0 = 1.f - wx1;
      float s = 0.f;
#pragma unroll
      for (int cy = 0; cy < 2; ++cy) {
        int yi = y0 + cy;
        float wyv = cy ? wy1 : wy0;
#pragma unroll
        for (int cx = 0; cx < 2; ++cx) {
          int xi = x0 + cx;
          float wgt = wyv * (cx ? wx1 : wx0);
          if (!((unsigned)yi < 48u && (unsigned)xi < 48u)) wgt = 0.f;
          int yc = yi < 0 ? 0 : (yi > 47 ? 47 : yi);
          int xc = xi < 0 ? 0 : (xi > 47 ? 47 : xi);
          uint2 u = *(const uint2*)(kvb + (size_t)(yc * WID + xc) * 384 + h * 16 + sub * 4);
          s += wgt * (qv.x * lo_bf(u.x) + qv.y * hi_bf(u.x) + qv.z * lo_bf(u.y) + qv.w * hi_bf(u.y));
        }
      }
      s += __shfl_xor(s, 1, 64);
      s += __shfl_xor(s, 2, 64);
      sc[c * 9 + kk] = s;
    }
  }

  // ---- softmax over 18 taps (in registers, redundant per sub-lane)
  {
    float m = -1e30f;
#pragma unroll
    for (int j = 0; j < 18; ++j) m = fmaxf(m, sc[j]);
    float sum = 0.f;
#pragma unroll
    for (int j = 0; j < 18; ++j) { float ev = __expf(sc[j] - m); sc[j] = ev; sum += ev; }
    float inv = 1.f / sum;
#pragma unroll
    for (int j = 0; j < 18; ++j) sc[j] *= inv;
  }

  // ---- V phase (offset group pk+6, v channels at +192)
  float ax = 0.f, ay = 0.f, az = 0.f, aw = 0.f;
#pragma unroll
  for (int c = 0; c < 2; ++c) {
    const float* offb = offs + ((size_t)(b * 2 + c)) * 216 * HW + n;
    const unsigned short* kvb = kvh + ((size_t)(b * 2 + c)) * HW * 384;
#pragma unroll
    for (int kk = 0; kk < 9; ++kk) {
      float oy = offb[(size_t)(((pk + 6) * 9 + kk) * 2 + 0) * HW];
      float ox = offb[(size_t)(((pk + 6) * 9 + kk) * 2 + 1) * HW];
      float py = (float)(hh - 1 + kk / 3) + oy;
      float px = (float)(ww - 1 + kk % 3) + ox;
      float y0f = floorf(py), x0f = floorf(px);
      int y0 = (int)y0f, x0 = (int)x0f;
      float wy1 = py - y0f, wx1 = px - x0f;
      float wy0 = 1.f - wy1, wx0 = 1.f - wx1;
      float at = sc[c * 9 + kk];
#pragma unroll
      for (int cy = 0; cy < 2; ++cy) {
        int yi = y0 + cy;
        float wyv = cy ? wy1 : wy0;
#pragma unroll
        for (int cx = 0; cx < 2; ++cx) {
          int xi = x0 + cx;
          float wgt = wyv * (cx ? wx1 : wx0);
          if (!((unsigned)yi < 48u && (unsigned)xi < 48u)) wgt = 0.f;
          int yc = yi < 0 ? 0 : (yi > 47 ? 47 : yi);
          int xc = xi < 0 ? 0 : (xi > 47 ? 47 : xi);
          uint2 u = *(const uint2*)(kvb + (size_t)(yc * WID + xc) * 384 + 192 + h * 16 + sub * 4);
          float cw = wgt * at;
          ax += cw * lo_bf(u.x); ay += cw * hi_bf(u.x);
          az += cw * lo_bf(u.y); aw += cw * hi_bf(u.y);
        }
      }
    }
  }

  float4 r; r.x = ax; r.y = ay; r.z = az; r.w = aw;
  *(float4*)(o_ws + ((size_t)b * HW + n) * 192 + h * 16 + sub * 4) = r;
}

// ---------------- MLP via MFMA: out[b][oc][n] = o + w2 @ gelu(w1 @ o + b1) + b2
__global__ __launch_bounds__(256) void mlp_mfma(
    const float* __restrict__ o_ws, const unsigned* __restrict__ wf,
    const float* __restrict__ b1, const float* __restrict__ b2,
    float* __restrict__ out)
{
  __shared__ unsigned ldsO[16 * 100];
  __shared__ unsigned ldsH[16 * 196];
  const unsigned* w1f = wf + 216 * 256;
  const unsigned* w2f = wf + 360 * 256;
  const int blk = blockIdx.x;
  const int b = blk / 144;
  const int n0 = (blk % 144) * 16;
  const int t = threadIdx.x;
  const int w = t >> 6, l = t & 63;

  for (int i = t; i < 16 * 96; i += 256) {
    int pix = i / 96, cp = i % 96;
    const float2 s = *(const float2*)(o_ws + ((size_t)(b * HW) + n0 + pix) * 192 + 2 * cp);
    ldsO[pix * 100 + cp] = pack_bf2(s.x, s.y);
  }
  __syncthreads();

  f32x4 acc1[6];
#pragma unroll
  for (int a = 0; a < 6; ++a) acc1[a] = (f32x4){0.f, 0.f, 0.f, 0.f};
#pragma unroll
  for (int ks = 0; ks < 6; ++ks) {
    bf16x8 af = *(const bf16x8*)&ldsO[(l & 15) * 100 + ks * 16 + (l >> 4) * 4];
#pragma unroll
    for (int nfi = 0; nfi < 6; ++nfi) {
      int nf = w * 6 + nfi;
      bf16x8 bfr = ((const bf16x8*)w1f)[(nf * 6 + ks) * 64 + l];
      acc1[nfi] = __builtin_amdgcn_mfma_f32_16x16x32_bf16(af, bfr, acc1[nfi], 0, 0, 0);
    }
  }

  {
    unsigned short* ldsHu = (unsigned short*)ldsH;
#pragma unroll
    for (int nfi = 0; nfi < 6; ++nfi) {
      int hc = (w * 6 + nfi) * 16 + (l & 15);
      float bs = b1[hc];
#pragma unroll
      for (int j = 0; j < 4; ++j) {
        int pix = (l >> 4) * 4 + j;
        float x = acc1[nfi][j] + bs;
        float gl = 0.5f * x * (1.f + erff(x * 0.70710678118654752f));
        ldsHu[pix * 392 + hc] = bf16_of(gl);
      }
    }
  }
  __syncthreads();

  f32x4 acc2[3];
#pragma unroll
  for (int a = 0; a < 3; ++a) acc2[a] = (f32x4){0.f, 0.f, 0.f, 0.f};
#pragma unroll
  for (int ks = 0; ks < 12; ++ks) {
    bf16x8 af = *(const bf16x8*)&ldsH[(l & 15) * 196 + ks * 16 + (l >> 4) * 4];
#pragma unroll
    for (int nfi = 0; nfi < 3; ++nfi) {
      int nf = w * 3 + nfi;
      bf16x8 bfr = ((const bf16x8*)w2f)[(nf * 12 + ks) * 64 + l];
      acc2[nfi] = __builtin_amdgcn_mfma_f32_16x16x32_bf16(af, bfr, acc2[nfi], 0, 0, 0);
    }
  }

#pragma unroll
  for (int nfi = 0; nfi < 3; ++nfi) {
    int oc = (w * 3 + nfi) * 16 + (l & 15);
    float bs = b2[oc];
#pragma unroll
    for (int j = 0; j < 4; ++j) {
      int pix = (l >> 4) * 4 + j;
      float res = o_ws[((size_t)(b * HW) + n0 + pix) * 192 + oc];
      out[((size_t)b * 192 + oc) * HW + n0 + pix] = acc2[nfi][j] + bs + res;
    }
  }
}

extern "C" void kernel_launch(void* const* d_in, const int* in_sizes, int n_in,
                              void* d_out, int out_size, void* d_ws, size_t ws_size,
                              hipStream_t stream) {
  const float* q = (const float*)d_in[0];
  const float* k = (const float*)d_in[1];
  const float* v = (const float*)d_in[2];
  const float* offset = (const float*)d_in[3];
  const float* wq = (const float*)d_in[4];
  const float* bq = (const float*)d_in[5];
  const float* wk = (const float*)d_in[6];
  const float* bk = (const float*)d_in[7];
  const float* wv = (const float*)d_in[8];
  const float* bv = (const float*)d_in[9];
  const float* w1 = (const float*)d_in[10];
  const float* b1 = (const float*)d_in[11];
  const float* w2 = (const float*)d_in[12];
  const float* b2 = (const float*)d_in[13];
  float* out = (float*)d_out;

  float* qp_t = (float*)d_ws;                                    // 4*2304*192 f32
  float* o_ws = qp_t + (size_t)4 * HW * 192;                     // 4*2304*192 f32
  unsigned short* kvh = (unsigned short*)(o_ws + (size_t)4 * HW * 192);  // 8*2304*384 bf16
  unsigned* wfb = (unsigned*)(kvh + (size_t)8 * HW * 384);       // 504 frags * 256 u32

  dim3 blk(256);
  prep_w<<<dim3(126), blk, 0, stream>>>(wq, wk, wv, w1, w2, wfb);
  proj_mfma<<<dim3(36, 20), blk, 0, stream>>>(q, k, v, wfb, bq, bk, bv, qp_t, kvh);
  attn_kernel<<<dim3(1728), blk, 0, stream>>>(qp_t, kvh, offset, o_ws);
  mlp_mfma<<<dim3(576), blk, 0, stream>>>(o_ws, wfb, b1, b2, out);
}

// Round 6
// 90.269 us; speedup vs baseline: 6.7533x; 1.0100x over previous
//
#include <hip/hip_runtime.h>

#define HW 2304
#define WID 48

typedef __attribute__((ext_vector_type(8))) short bf16x8;
typedef __attribute__((ext_vector_type(4))) float f32x4;
typedef __attribute__((ext_vector_type(2))) _Float16 half2v;

__device__ __forceinline__ half2v pk_h2(float lo, float hi) {
  return __builtin_bit_cast(half2v, __builtin_amdgcn_cvt_pkrtz(lo, hi));
}

__device__ __forceinline__ unsigned pack_bf2(float lo, float hi) {
  unsigned a = __builtin_bit_cast(unsigned, lo);
  unsigned b = __builtin_bit_cast(unsigned, hi);
  a = (a + 0x7FFFu + ((a >> 16) & 1u)) >> 16;
  b = (b + 0x7FFFu + ((b >> 16) & 1u)) >> 16;
  return a | (b << 16);
}
__device__ __forceinline__ unsigned short bf16_of(float x) {
  unsigned u = __builtin_bit_cast(unsigned, x);
  u = (u + 0x7FFFu + ((u >> 16) & 1u)) >> 16;
  return (unsigned short)u;
}
__device__ __forceinline__ unsigned short f16_of(float x) {
  _Float16 h = (_Float16)x;
  return __builtin_bit_cast(unsigned short, h);
}
__device__ __forceinline__ float lo_bf(unsigned u) {
  return __builtin_bit_cast(float, u << 16);
}
__device__ __forceinline__ float hi_bf(unsigned u) {
  return __builtin_bit_cast(float, u & 0xFFFF0000u);
}

// ---------------- Weight prep: fp32 [N][K] -> fragment-ordered bf16
__global__ __launch_bounds__(256) void prep_w(
    const float* __restrict__ wq, const float* __restrict__ wk,
    const float* __restrict__ wv, const float* __restrict__ w1,
    const float* __restrict__ w2, unsigned* __restrict__ wf)
{
  int fid = blockIdx.x * 4 + (threadIdx.x >> 6);
  int l = threadIdx.x & 63;
  const float* src; int K; int base;
  if (fid < 72)       { src = wq; K = 192; base = 0; }
  else if (fid < 144) { src = wk; K = 192; base = 72; }
  else if (fid < 216) { src = wv; K = 192; base = 144; }
  else if (fid < 360) { src = w1; K = 192; base = 216; }
  else                { src = w2; K = 384; base = 360; }
  int local = fid - base;
  int KS = K / 32;
  int nf = local / KS, ks = local % KS;
  int row = nf * 16 + (l & 15);
  int c0 = ks * 32 + (l >> 4) * 8;
  const float* p = src + (size_t)row * K + c0;
  float4 v0 = *(const float4*)p;
  float4 v1 = *(const float4*)(p + 4);
  unsigned* dst = wf + ((size_t)fid * 64 + l) * 4;
  dst[0] = pack_bf2(v0.x, v0.y);
  dst[1] = pack_bf2(v0.z, v0.w);
  dst[2] = pack_bf2(v1.x, v1.y);
  dst[3] = pack_bf2(v1.z, v1.w);
}

// ---------------- Sampling-record precompute: one thread per (b,c,dg,tap,n)
// rec = { idx01, idx23 (4 x u16 clamped spatial index), w01, w23 (4 x f16 weights) }
__global__ __launch_bounds__(256) void prep_samp(
    const float* __restrict__ offs, uint4* __restrict__ recs)
{
  int gid = blockIdx.x * 256 + threadIdx.x;   // < 4*2*12*9*2304
  int n = gid % HW;
  int r = gid / HW;          // bc*108 + dg*9 + kk
  int kk = r % 9;
  int dgr = r / 9;
  int dg = dgr % 12;
  int bc = dgr / 12;
  int hh = n / WID, ww = n % WID;
  const float* ob = offs + ((size_t)bc * 216 + (size_t)(dg * 9 + kk) * 2) * HW + n;
  float oy = ob[0];
  float ox = ob[HW];
  float py = (float)(hh - 1 + kk / 3) + oy;
  float px = (float)(ww - 1 + kk % 3) + ox;
  float y0f = floorf(py), x0f = floorf(px);
  int y0 = (int)y0f, x0 = (int)x0f;
  float wy1 = py - y0f, wx1 = px - x0f;
  float wy0 = 1.f - wy1, wx0 = 1.f - wx1;

  unsigned ip[2];
  float wv[4];
#pragma unroll
  for (int cy = 0; cy < 2; ++cy) {
    int yi = y0 + cy;
    float wyv = cy ? wy1 : wy0;
    int yc = yi < 0 ? 0 : (yi > 47 ? 47 : yi);
    bool vy = (unsigned)yi < 48u;
#pragma unroll
    for (int cx = 0; cx < 2; ++cx) {
      int xi = x0 + cx;
      float wxv = cx ? wx1 : wx0;
      int xc = xi < 0 ? 0 : (xi > 47 ? 47 : xi);
      bool vx = (unsigned)xi < 48u;
      float wgt = (vy && vx) ? wyv * wxv : 0.f;
      int ci = cy * 2 + cx;
      wv[ci] = wgt;
      ((unsigned short*)ip)[ci] = (unsigned short)(yc * WID + xc);
    }
  }
  uint4 rc;
  rc.x = ip[0];
  rc.y = ip[1];
  rc.z = __builtin_bit_cast(unsigned, pk_h2(wv[0], wv[1]));
  rc.w = __builtin_bit_cast(unsigned, pk_h2(wv[2], wv[3]));
  recs[gid] = rc;
}

// ---------------- Projection via MFMA. q slab -> fp32 qp [B][HW][192];
// k slabs -> f16, v slabs -> bf16 in kvh [B*2][HW][384] (k at 0, v at +192)
__global__ __launch_bounds__(256) void proj_mfma(
    const float* __restrict__ q, const float* __restrict__ k, const float* __restrict__ v,
    const unsigned* __restrict__ wf,
    const float* __restrict__ bq, const float* __restrict__ bk, const float* __restrict__ bv,
    float* __restrict__ qp, unsigned short* __restrict__ kvh)
{
  __shared__ unsigned lds[64 * 100];
  int slab = blockIdx.y;
  const float* in; const unsigned* wfr; const float* bias;
  float* outf = nullptr; unsigned short* outh = nullptr;
  int mode;
  if (slab < 4) {
    in = q + (size_t)slab * 192 * HW; wfr = wf; bias = bq;
    outf = qp + (size_t)slab * HW * 192; mode = 0;
  } else if (slab < 12) {
    int c = slab - 4;
    in = k + (size_t)c * 192 * HW; wfr = wf + 72 * 256; bias = bk;
    outh = kvh + (size_t)c * HW * 384; mode = 1;
  } else {
    int c = slab - 12;
    in = v + (size_t)c * 192 * HW; wfr = wf + 144 * 256; bias = bv;
    outh = kvh + (size_t)c * HW * 384 + 192; mode = 2;
  }
  const int n0 = blockIdx.x * 64;
  const int t = threadIdx.x;
  const int w = t >> 6, l = t & 63;

  {
    int pix = t & 63;
    int cp0 = t >> 6;
    const float* s0 = in + n0 + pix;
#pragma unroll
    for (int i = 0; i < 24; ++i) {
      int cp = cp0 * 24 + i;
      float lo = s0[(size_t)(2 * cp) * HW];
      float hi = s0[(size_t)(2 * cp + 1) * HW];
      lds[pix * 100 + cp] = pack_bf2(lo, hi);
    }
  }

  bf16x8 wfrag[6][3];
#pragma unroll
  for (int ks = 0; ks < 6; ++ks)
#pragma unroll
    for (int nfi = 0; nfi < 3; ++nfi) {
      int nf = w * 3 + nfi;
      wfrag[ks][nfi] = ((const bf16x8*)wfr)[(nf * 6 + ks) * 64 + l];
    }

  __syncthreads();

  f32x4 acc[3][4];
#pragma unroll
  for (int a = 0; a < 3; ++a)
#pragma unroll
    for (int m = 0; m < 4; ++m) acc[a][m] = (f32x4){0.f, 0.f, 0.f, 0.f};

#pragma unroll
  for (int ks = 0; ks < 6; ++ks) {
    bf16x8 af[4];
#pragma unroll
    for (int mf = 0; mf < 4; ++mf)
      af[mf] = *(const bf16x8*)&lds[(mf * 16 + (l & 15)) * 100 + ks * 16 + (l >> 4) * 4];
#pragma unroll
    for (int nfi = 0; nfi < 3; ++nfi)
#pragma unroll
      for (int mf = 0; mf < 4; ++mf)
        acc[nfi][mf] = __builtin_amdgcn_mfma_f32_16x16x32_bf16(af[mf], wfrag[ks][nfi], acc[nfi][mf], 0, 0, 0);
  }

#pragma unroll
  for (int nfi = 0; nfi < 3; ++nfi) {
    int oc = (w * 3 + nfi) * 16 + (l & 15);
    float bs = bias[oc];
    if (mode == 0) {
#pragma unroll
      for (int mf = 0; mf < 4; ++mf) {
        int pixb = n0 + mf * 16 + (l >> 4) * 4;
#pragma unroll
        for (int j = 0; j < 4; ++j)
          outf[(size_t)(pixb + j) * 192 + oc] = acc[nfi][mf][j] + bs;
      }
    } else if (mode == 1) {
#pragma unroll
      for (int mf = 0; mf < 4; ++mf) {
        int pixb = n0 + mf * 16 + (l >> 4) * 4;
#pragma unroll
        for (int j = 0; j < 4; ++j)
          outh[(size_t)(pixb + j) * 384 + oc] = f16_of(acc[nfi][mf][j] + bs);
      }
    } else {
#pragma unroll
      for (int mf = 0; mf < 4; ++mf) {
        int pixb = n0 + mf * 16 + (l >> 4) * 4;
#pragma unroll
        for (int j = 0; j < 4; ++j)
          outh[(size_t)(pixb + j) * 384 + oc] = bf16_of(acc[nfi][mf][j] + bs);
      }
    }
  }
}

// ---------------- Deformable attention: block = (b, half, head-pair, 32-pixel tile)
// 8 lanes per pixel: 2 heads (hi) x 4 subs (4 channels each). Records precomputed.
// qp f32 [B][HW][192]; kvh [B*2][HW][384] (k f16 / v bf16); recs per (bc,dg,tap,n)
__global__ __launch_bounds__(256) void attn_kernel(
    const float* __restrict__ qp, const unsigned short* __restrict__ kvh,
    const uint4* __restrict__ recs, float* __restrict__ o_ws)
{
  const int t = threadIdx.x;
  const int g = blockIdx.x & 7;          // (b, half) -> XCD-resident KV slab
  const int pos = blockIdx.x >> 3;       // 0..215
  const int b = g >> 1;
  const int half = g & 1;
  const int pk = pos / 36;
  const int tile = pos % 36;
  const int sub = t & 3;
  const int hi = (t >> 2) & 1;
  const int pix = t >> 3;
  const int n = half * 1152 + tile * 32 + pix;
  const int h = 2 * pk + hi;

  half2v qh0, qh1;
  {
    float4 vv = *(const float4*)(qp + ((size_t)b * HW + n) * 192 + h * 16 + sub * 4);
    qh0 = pk_h2(vv.x * 0.25f, vv.y * 0.25f);
    qh1 = pk_h2(vv.z * 0.25f, vv.w * 0.25f);
  }

  float sc[18];

  // ---- K phase: dg = pk, f16 K channels
#pragma unroll
  for (int c = 0; c < 2; ++c) {
    const unsigned short* kb = kvh + ((size_t)(b * 2 + c)) * HW * 384 + h * 16 + sub * 4;
    const uint4* rb = recs + ((size_t)((b * 2 + c) * 12 + pk) * 9) * HW + n;
#pragma unroll
    for (int kk = 0; kk < 9; ++kk) {
      uint4 rc = rb[(size_t)kk * HW];
      half2v w01 = __builtin_bit_cast(half2v, rc.z);
      half2v w23 = __builtin_bit_cast(half2v, rc.w);
      float s = 0.f;
#pragma unroll
      for (int ci = 0; ci < 4; ++ci) {
        unsigned pr = (ci < 2) ? rc.x : rc.y;
        unsigned idx = (ci & 1) ? (pr >> 16) : (pr & 0xFFFFu);
        _Float16 wh = (ci == 0) ? w01.x : (ci == 1) ? w01.y : (ci == 2) ? w23.x : w23.y;
        uint2 u = *(const uint2*)(kb + (size_t)idx * 384);
        float d = __builtin_amdgcn_fdot2(qh0, __builtin_bit_cast(half2v, u.x), 0.f, false);
        d = __builtin_amdgcn_fdot2(qh1, __builtin_bit_cast(half2v, u.y), d, false);
        s += (float)wh * d;
      }
      s += __shfl_xor(s, 1, 64);
      s += __shfl_xor(s, 2, 64);
      sc[c * 9 + kk] = s;
    }
  }

  // ---- softmax over 18 taps (in registers, redundant per sub-lane)
  {
    float m = -1e30f;
#pragma unroll
    for (int j = 0; j < 18; ++j) m = fmaxf(m, sc[j]);
    float sum = 0.f;
#pragma unroll
    for (int j = 0; j < 18; ++j) { float ev = __expf(sc[j] - m); sc[j] = ev; sum += ev; }
    float inv = 1.f / sum;
#pragma unroll
    for (int j = 0; j < 18; ++j) sc[j] *= inv;
  }

  // ---- V phase: dg = pk + 6, bf16 V channels at +192
  float ax = 0.f, ay = 0.f, az = 0.f, aw = 0.f;
#pragma unroll
  for (int c = 0; c < 2; ++c) {
    const unsigned short* vb = kvh + ((size_t)(b * 2 + c)) * HW * 384 + 192 + h * 16 + sub * 4;
    const uint4* rb = recs + ((size_t)((b * 2 + c) * 12 + pk + 6) * 9) * HW + n;
#pragma unroll
    for (int kk = 0; kk < 9; ++kk) {
      uint4 rc = rb[(size_t)kk * HW];
      half2v w01 = __builtin_bit_cast(half2v, rc.z);
      half2v w23 = __builtin_bit_cast(half2v, rc.w);
      float at = sc[c * 9 + kk];
#pragma unroll
      for (int ci = 0; ci < 4; ++ci) {
        unsigned pr = (ci < 2) ? rc.x : rc.y;
        unsigned idx = (ci & 1) ? (pr >> 16) : (pr & 0xFFFFu);
        _Float16 wh = (ci == 0) ? w01.x : (ci == 1) ? w01.y : (ci == 2) ? w23.x : w23.y;
        uint2 u = *(const uint2*)(vb + (size_t)idx * 384);
        float cw = (float)wh * at;
        ax += cw * lo_bf(u.x); ay += cw * hi_bf(u.x);
        az += cw * lo_bf(u.y); aw += cw * hi_bf(u.y);
      }
    }
  }

  float4 r; r.x = ax; r.y = ay; r.z = az; r.w = aw;
  *(float4*)(o_ws + ((size_t)b * HW + n) * 192 + h * 16 + sub * 4) = r;
}

// ---------------- MLP via MFMA: out[b][oc][n] = o + w2 @ gelu(w1 @ o + b1) + b2
__global__ __launch_bounds__(256) void mlp_mfma(
    const float* __restrict__ o_ws, const unsigned* __restrict__ wf,
    const float* __restrict__ b1, const float* __restrict__ b2,
    float* __restrict__ out)
{
  __shared__ unsigned ldsO[16 * 100];
  __shared__ unsigned ldsH[16 * 196];
  const unsigned* w1f = wf + 216 * 256;
  const unsigned* w2f = wf + 360 * 256;
  const int blk = blockIdx.x;
  const int b = blk / 144;
  const int n0 = (blk % 144) * 16;
  const int t = threadIdx.x;
  const int w = t >> 6, l = t & 63;

  for (int i = t; i < 16 * 96; i += 256) {
    int pix = i / 96, cp = i % 96;
    const float2 s = *(const float2*)(o_ws + ((size_t)(b * HW) + n0 + pix) * 192 + 2 * cp);
    ldsO[pix * 100 + cp] = pack_bf2(s.x, s.y);
  }
  __syncthreads();

  f32x4 acc1[6];
#pragma unroll
  for (int a = 0; a < 6; ++a) acc1[a] = (f32x4){0.f, 0.f, 0.f, 0.f};
#pragma unroll
  for (int ks = 0; ks < 6; ++ks) {
    bf16x8 af = *(const bf16x8*)&ldsO[(l & 15) * 100 + ks * 16 + (l >> 4) * 4];
#pragma unroll
    for (int nfi = 0; nfi < 6; ++nfi) {
      int nf = w * 6 + nfi;
      bf16x8 bfr = ((const bf16x8*)w1f)[(nf * 6 + ks) * 64 + l];
      acc1[nfi] = __builtin_amdgcn_mfma_f32_16x16x32_bf16(af, bfr, acc1[nfi], 0, 0, 0);
    }
  }

  {
    unsigned short* ldsHu = (unsigned short*)ldsH;
#pragma unroll
    for (int nfi = 0; nfi < 6; ++nfi) {
      int hc = (w * 6 + nfi) * 16 + (l & 15);
      float bs = b1[hc];
#pragma unroll
      for (int j = 0; j < 4; ++j) {
        int pix = (l >> 4) * 4 + j;
        float x = acc1[nfi][j] + bs;
        float gl = 0.5f * x * (1.f + erff(x * 0.70710678118654752f));
        ldsHu[pix * 392 + hc] = bf16_of(gl);
      }
    }
  }
  __syncthreads();

  f32x4 acc2[3];
#pragma unroll
  for (int a = 0; a < 3; ++a) acc2[a] = (f32x4){0.f, 0.f, 0.f, 0.f};
#pragma unroll
  for (int ks = 0; ks < 12; ++ks) {
    bf16x8 af = *(const bf16x8*)&ldsH[(l & 15) * 196 + ks * 16 + (l >> 4) * 4];
#pragma unroll
    for (int nfi = 0; nfi < 3; ++nfi) {
      int nf = w * 3 + nfi;
      bf16x8 bfr = ((const bf16x8*)w2f)[(nf * 12 + ks) * 64 + l];
      acc2[nfi] = __builtin_amdgcn_mfma_f32_16x16x32_bf16(af, bfr, acc2[nfi], 0, 0, 0);
    }
  }

#pragma unroll
  for (int nfi = 0; nfi < 3; ++nfi) {
    int oc = (w * 3 + nfi) * 16 + (l & 15);
    float bs = b2[oc];
#pragma unroll
    for (int j = 0; j < 4; ++j) {
      int pix = (l >> 4) * 4 + j;
      float res = o_ws[((size_t)(b * HW) + n0 + pix) * 192 + oc];
      out[((size_t)b * 192 + oc) * HW + n0 + pix] = acc2[nfi][j] + bs + res;
    }
  }
}

extern "C" void kernel_launch(void* const* d_in, const int* in_sizes, int n_in,
                              void* d_out, int out_size, void* d_ws, size_t ws_size,
                              hipStream_t stream) {
  const float* q = (const float*)d_in[0];
  const float* k = (const float*)d_in[1];
  const float* v = (const float*)d_in[2];
  const float* offset = (const float*)d_in[3];
  const float* wq = (const float*)d_in[4];
  const float* bq = (const float*)d_in[5];
  const float* wk = (const float*)d_in[6];
  const float* bk = (const float*)d_in[7];
  const float* wv = (const float*)d_in[8];
  const float* bv = (const float*)d_in[9];
  const float* w1 = (const float*)d_in[10];
  const float* b1 = (const float*)d_in[11];
  const float* w2 = (const float*)d_in[12];
  const float* b2 = (const float*)d_in[13];
  float* out = (float*)d_out;

  float* qp_t = (float*)d_ws;                                    // 4*2304*192 f32
  float* o_ws = qp_t + (size_t)4 * HW * 192;                     // 4*2304*192 f32
  unsigned short* kvh = (unsigned short*)(o_ws + (size_t)4 * HW * 192);  // 8*2304*384 u16
  unsigned* wfb = (unsigned*)(kvh + (size_t)8 * HW * 384);       // 504*256 u32
  uint4* recs = (uint4*)(wfb + 504 * 256);                       // 1,990,656 * 16B

  dim3 blk(256);
  prep_w<<<dim3(126), blk, 0, stream>>>(wq, wk, wv, w1, w2, wfb);
  prep_samp<<<dim3(7776), blk, 0, stream>>>(offset, recs);
  proj_mfma<<<dim3(36, 20), blk, 0, stream>>>(q, k, v, wfb, bq, bk, bv, qp_t, kvh);
  attn_kernel<<<dim3(1728), blk, 0, stream>>>(qp_t, kvh, recs, o_ws);
  mlp_mfma<<<dim3(576), blk, 0, stream>>>(o_ws, wfb, b1, b2, out);
}

// Round 8
// 76.521 us; speedup vs baseline: 7.9666x; 1.1797x over previous
//
#include <hip/hip_runtime.h>

#define HW 2304
#define WID 48

typedef __attribute__((ext_vector_type(8))) short bf16x8;
typedef __attribute__((ext_vector_type(4))) float f32x4;
typedef __attribute__((ext_vector_type(2))) _Float16 half2v;

__device__ __forceinline__ half2v pk_h2(float lo, float hi) {
  return __builtin_bit_cast(half2v, __builtin_amdgcn_cvt_pkrtz(lo, hi));
}

__device__ __forceinline__ unsigned pack_bf2(float lo, float hi) {
  unsigned a = __builtin_bit_cast(unsigned, lo);
  unsigned b = __builtin_bit_cast(unsigned, hi);
  a = (a + 0x7FFFu + ((a >> 16) & 1u)) >> 16;
  b = (b + 0x7FFFu + ((b >> 16) & 1u)) >> 16;
  return a | (b << 16);
}
__device__ __forceinline__ unsigned short bf16_of(float x) {
  unsigned u = __builtin_bit_cast(unsigned, x);
  u = (u + 0x7FFFu + ((u >> 16) & 1u)) >> 16;
  return (unsigned short)u;
}
__device__ __forceinline__ unsigned short f16_of(float x) {
  _Float16 h = (_Float16)x;
  return __builtin_bit_cast(unsigned short, h);
}
__device__ __forceinline__ float lo_bf(unsigned u) {
  return __builtin_bit_cast(float, u << 16);
}
__device__ __forceinline__ float hi_bf(unsigned u) {
  return __builtin_bit_cast(float, u & 0xFFFF0000u);
}

// ---------------- Weight prep: fp32 [N][K] -> fragment-ordered bf16
__global__ __launch_bounds__(256) void prep_w(
    const float* __restrict__ wq, const float* __restrict__ wk,
    const float* __restrict__ wv, const float* __restrict__ w1,
    const float* __restrict__ w2, unsigned* __restrict__ wf)
{
  int fid = blockIdx.x * 4 + (threadIdx.x >> 6);
  int l = threadIdx.x & 63;
  const float* src; int K; int base;
  if (fid < 72)       { src = wq; K = 192; base = 0; }
  else if (fid < 144) { src = wk; K = 192; base = 72; }
  else if (fid < 216) { src = wv; K = 192; base = 144; }
  else if (fid < 360) { src = w1; K = 192; base = 216; }
  else                { src = w2; K = 384; base = 360; }
  int local = fid - base;
  int KS = K / 32;
  int nf = local / KS, ks = local % KS;
  int row = nf * 16 + (l & 15);
  int c0 = ks * 32 + (l >> 4) * 8;
  const float* p = src + (size_t)row * K + c0;
  float4 v0 = *(const float4*)p;
  float4 v1 = *(const float4*)(p + 4);
  unsigned* dst = wf + ((size_t)fid * 64 + l) * 4;
  dst[0] = pack_bf2(v0.x, v0.y);
  dst[1] = pack_bf2(v0.z, v0.w);
  dst[2] = pack_bf2(v1.x, v1.y);
  dst[3] = pack_bf2(v1.z, v1.w);
}

// ---------------- Projection via MFMA. q slab -> fp32 qp [B][HW][192];
// k slabs -> f16, v slabs -> bf16 in kvh [B*2][HW][384] (k at 0, v at +192)
__global__ __launch_bounds__(256) void proj_mfma(
    const float* __restrict__ q, const float* __restrict__ k, const float* __restrict__ v,
    const unsigned* __restrict__ wf,
    const float* __restrict__ bq, const float* __restrict__ bk, const float* __restrict__ bv,
    float* __restrict__ qp, unsigned short* __restrict__ kvh)
{
  __shared__ unsigned lds[64 * 100];
  int slab = blockIdx.y;
  const float* in; const unsigned* wfr; const float* bias;
  float* outf = nullptr; unsigned short* outh = nullptr;
  int mode;
  if (slab < 4) {
    in = q + (size_t)slab * 192 * HW; wfr = wf; bias = bq;
    outf = qp + (size_t)slab * HW * 192; mode = 0;
  } else if (slab < 12) {
    int c = slab - 4;
    in = k + (size_t)c * 192 * HW; wfr = wf + 72 * 256; bias = bk;
    outh = kvh + (size_t)c * HW * 384; mode = 1;
  } else {
    int c = slab - 12;
    in = v + (size_t)c * 192 * HW; wfr = wf + 144 * 256; bias = bv;
    outh = kvh + (size_t)c * HW * 384 + 192; mode = 2;
  }
  const int n0 = blockIdx.x * 64;
  const int t = threadIdx.x;
  const int w = t >> 6, l = t & 63;

  {
    int pix = t & 63;
    int cp0 = t >> 6;
    const float* s0 = in + n0 + pix;
#pragma unroll
    for (int i = 0; i < 24; ++i) {
      int cp = cp0 * 24 + i;
      float lo = s0[(size_t)(2 * cp) * HW];
      float hi = s0[(size_t)(2 * cp + 1) * HW];
      lds[pix * 100 + cp] = pack_bf2(lo, hi);
    }
  }

  bf16x8 wfrag[6][3];
#pragma unroll
  for (int ks = 0; ks < 6; ++ks)
#pragma unroll
    for (int nfi = 0; nfi < 3; ++nfi) {
      int nf = w * 3 + nfi;
      wfrag[ks][nfi] = ((const bf16x8*)wfr)[(nf * 6 + ks) * 64 + l];
    }

  __syncthreads();

  f32x4 acc[3][4];
#pragma unroll
  for (int a = 0; a < 3; ++a)
#pragma unroll
    for (int m = 0; m < 4; ++m) acc[a][m] = (f32x4){0.f, 0.f, 0.f, 0.f};

#pragma unroll
  for (int ks = 0; ks < 6; ++ks) {
    bf16x8 af[4];
#pragma unroll
    for (int mf = 0; mf < 4; ++mf)
      af[mf] = *(const bf16x8*)&lds[(mf * 16 + (l & 15)) * 100 + ks * 16 + (l >> 4) * 4];
#pragma unroll
    for (int nfi = 0; nfi < 3; ++nfi)
#pragma unroll
      for (int mf = 0; mf < 4; ++mf)
        acc[nfi][mf] = __builtin_amdgcn_mfma_f32_16x16x32_bf16(af[mf], wfrag[ks][nfi], acc[nfi][mf], 0, 0, 0);
  }

#pragma unroll
  for (int nfi = 0; nfi < 3; ++nfi) {
    int oc = (w * 3 + nfi) * 16 + (l & 15);
    float bs = bias[oc];
    if (mode == 0) {
#pragma unroll
      for (int mf = 0; mf < 4; ++mf) {
        int pixb = n0 + mf * 16 + (l >> 4) * 4;
#pragma unroll
        for (int j = 0; j < 4; ++j)
          outf[(size_t)(pixb + j) * 192 + oc] = acc[nfi][mf][j] + bs;
      }
    } else if (mode == 1) {
#pragma unroll
      for (int mf = 0; mf < 4; ++mf) {
        int pixb = n0 + mf * 16 + (l >> 4) * 4;
#pragma unroll
        for (int j = 0; j < 4; ++j)
          outh[(size_t)(pixb + j) * 384 + oc] = f16_of(acc[nfi][mf][j] + bs);
      }
    } else {
#pragma unroll
      for (int mf = 0; mf < 4; ++mf) {
        int pixb = n0 + mf * 16 + (l >> 4) * 4;
#pragma unroll
        for (int j = 0; j < 4; ++j)
          outh[(size_t)(pixb + j) * 384 + oc] = bf16_of(acc[nfi][mf][j] + bs);
      }
    }
  }
}

// ---------------- Deformable attention: block = (b, half, head-pair, 32-pixel tile)
// 8 lanes per pixel: 2 heads (hi) x 4 subs (4 channels each).
// Sampling records computed IN-BLOCK into LDS (each record used only here).
// qp f32 [B][HW][192]; kvh [B*2][HW][384] (k f16 / v bf16); offs f32 [B*2][216][HW]
__global__ __launch_bounds__(256, 4) void attn_kernel(
    const float* __restrict__ qp, const unsigned short* __restrict__ kvh,
    const float* __restrict__ offs, float* __restrict__ o_ws)
{
  __shared__ uint4 rec[2][2][9][32];   // [dgsel][clip][tap][pix]
  const int t = threadIdx.x;
  const int g = blockIdx.x & 7;          // (b, half) -> XCD-resident KV slab
  const int pos = blockIdx.x >> 3;       // 0..215
  const int b = g >> 1;
  const int half = g & 1;
  const int pk = pos / 36;
  const int tile = pos % 36;
  const int n_base = half * 1152 + tile * 32;

  // ---- in-block record computation: 1152 records, ~4.5 per thread
#pragma unroll
  for (int i = 0; i < 5; ++i) {
    int rid = t + i * 256;
    if (rid < 1152) {
      int rpix = rid & 31;
      int rest = rid >> 5;               // 0..35 = (dgsel, clip, tap)
      int rtap = rest % 9;
      int rq = rest / 9;                 // 0..3
      int rclip = rq & 1;
      int dgsel = rq >> 1;
      int rn = n_base + rpix;
      int rh = rn / WID, rw = rn % WID;
      int dg = pk + dgsel * 6;
      const float* ob = offs + ((size_t)(b * 2 + rclip) * 216 + (size_t)(dg * 9 + rtap) * 2) * HW + rn;
      float oy = ob[0];
      float ox = ob[HW];
      float py = (float)(rh - 1 + rtap / 3) + oy;
      float px = (float)(rw - 1 + rtap % 3) + ox;
      float y0f = floorf(py), x0f = floorf(px);
      int y0 = (int)y0f, x0 = (int)x0f;
      float wy1 = py - y0f, wx1 = px - x0f;
      float wy0 = 1.f - wy1, wx0 = 1.f - wx1;
      unsigned ip[2];
      float wv[4];
#pragma unroll
      for (int cy = 0; cy < 2; ++cy) {
        int yi = y0 + cy;
        float wyv = cy ? wy1 : wy0;
        int yc = yi < 0 ? 0 : (yi > 47 ? 47 : yi);
        bool vy = (unsigned)yi < 48u;
#pragma unroll
        for (int cx = 0; cx < 2; ++cx) {
          int xi = x0 + cx;
          float wxv = cx ? wx1 : wx0;
          int xc = xi < 0 ? 0 : (xi > 47 ? 47 : xi);
          bool vx = (unsigned)xi < 48u;
          float wgt = (vy && vx) ? wyv * wxv : 0.f;
          int ci = cy * 2 + cx;
          wv[ci] = wgt;
          ((unsigned short*)ip)[ci] = (unsigned short)(yc * WID + xc);
        }
      }
      uint4 rc;
      rc.x = ip[0];
      rc.y = ip[1];
      rc.z = __builtin_bit_cast(unsigned, pk_h2(wv[0], wv[1]));
      rc.w = __builtin_bit_cast(unsigned, pk_h2(wv[2], wv[3]));
      rec[dgsel][rclip][rtap][rpix] = rc;
    }
  }

  const int sub = t & 3;
  const int hi = (t >> 2) & 1;
  const int pix = t >> 3;
  const int n = n_base + pix;
  const int h = 2 * pk + hi;

  half2v qh0, qh1;
  {
    float4 vv = *(const float4*)(qp + ((size_t)b * HW + n) * 192 + h * 16 + sub * 4);
    qh0 = pk_h2(vv.x * 0.25f, vv.y * 0.25f);
    qh1 = pk_h2(vv.z * 0.25f, vv.w * 0.25f);
  }

  __syncthreads();

  float sc[18];

  // ---- K phase: dg = pk, f16 K channels
#pragma unroll
  for (int c = 0; c < 2; ++c) {
    const unsigned short* kb = kvh + ((size_t)(b * 2 + c)) * HW * 384 + h * 16 + sub * 4;
#pragma unroll
    for (int kk = 0; kk < 9; ++kk) {
      uint4 rc = rec[0][c][kk][pix];
      half2v w01 = __builtin_bit_cast(half2v, rc.z);
      half2v w23 = __builtin_bit_cast(half2v, rc.w);
      float s = 0.f;
#pragma unroll
      for (int ci = 0; ci < 4; ++ci) {
        unsigned pr = (ci < 2) ? rc.x : rc.y;
        unsigned idx = (ci & 1) ? (pr >> 16) : (pr & 0xFFFFu);
        _Float16 wh = (ci == 0) ? w01.x : (ci == 1) ? w01.y : (ci == 2) ? w23.x : w23.y;
        uint2 u = *(const uint2*)(kb + (size_t)idx * 384);
        float d = __builtin_amdgcn_fdot2(qh0, __builtin_bit_cast(half2v, u.x), 0.f, false);
        d = __builtin_amdgcn_fdot2(qh1, __builtin_bit_cast(half2v, u.y), d, false);
        s += (float)wh * d;
      }
      s += __shfl_xor(s, 1, 64);
      s += __shfl_xor(s, 2, 64);
      sc[c * 9 + kk] = s;
    }
  }

  // ---- softmax over 18 taps (in registers, redundant per sub-lane)
  {
    float m = -1e30f;
#pragma unroll
    for (int j = 0; j < 18; ++j) m = fmaxf(m, sc[j]);
    float sum = 0.f;
#pragma unroll
    for (int j = 0; j < 18; ++j) { float ev = __expf(sc[j] - m); sc[j] = ev; sum += ev; }
    float inv = 1.f / sum;
#pragma unroll
    for (int j = 0; j < 18; ++j) sc[j] *= inv;
  }

  // ---- V phase: dg = pk + 6, bf16 V channels at +192
  float ax = 0.f, ay = 0.f, az = 0.f, aw = 0.f;
#pragma unroll
  for (int c = 0; c < 2; ++c) {
    const unsigned short* vb = kvh + ((size_t)(b * 2 + c)) * HW * 384 + 192 + h * 16 + sub * 4;
#pragma unroll
    for (int kk = 0; kk < 9; ++kk) {
      uint4 rc = rec[1][c][kk][pix];
      half2v w01 = __builtin_bit_cast(half2v, rc.z);
      half2v w23 = __builtin_bit_cast(half2v, rc.w);
      float at = sc[c * 9 + kk];
#pragma unroll
      for (int ci = 0; ci < 4; ++ci) {
        unsigned pr = (ci < 2) ? rc.x : rc.y;
        unsigned idx = (ci & 1) ? (pr >> 16) : (pr & 0xFFFFu);
        _Float16 wh = (ci == 0) ? w01.x : (ci == 1) ? w01.y : (ci == 2) ? w23.x : w23.y;
        uint2 u = *(const uint2*)(vb + (size_t)idx * 384);
        float cw = (float)wh * at;
        ax += cw * lo_bf(u.x); ay += cw * hi_bf(u.x);
        az += cw * lo_bf(u.y); aw += cw * hi_bf(u.y);
      }
    }
  }

  float4 r; r.x = ax; r.y = ay; r.z = az; r.w = aw;
  *(float4*)(o_ws + ((size_t)b * HW + n) * 192 + h * 16 + sub * 4) = r;
}

// ---------------- MLP via MFMA: out[b][oc][n] = o + w2 @ gelu(w1 @ o + b1) + b2
__global__ __launch_bounds__(256) void mlp_mfma(
    const float* __restrict__ o_ws, const unsigned* __restrict__ wf,
    const float* __restrict__ b1, const float* __restrict__ b2,
    float* __restrict__ out)
{
  __shared__ unsigned ldsO[16 * 100];
  __shared__ unsigned ldsH[16 * 196];
  const unsigned* w1f = wf + 216 * 256;
  const unsigned* w2f = wf + 360 * 256;
  const int blk = blockIdx.x;
  const int b = blk / 144;
  const int n0 = (blk % 144) * 16;
  const int t = threadIdx.x;
  const int w = t >> 6, l = t & 63;

  for (int i = t; i < 16 * 96; i += 256) {
    int pix = i / 96, cp = i % 96;
    const float2 s = *(const float2*)(o_ws + ((size_t)(b * HW) + n0 + pix) * 192 + 2 * cp);
    ldsO[pix * 100 + cp] = pack_bf2(s.x, s.y);
  }
  __syncthreads();

  f32x4 acc1[6];
#pragma unroll
  for (int a = 0; a < 6; ++a) acc1[a] = (f32x4){0.f, 0.f, 0.f, 0.f};
#pragma unroll
  for (int ks = 0; ks < 6; ++ks) {
    bf16x8 af = *(const bf16x8*)&ldsO[(l & 15) * 100 + ks * 16 + (l >> 4) * 4];
#pragma unroll
    for (int nfi = 0; nfi < 6; ++nfi) {
      int nf = w * 6 + nfi;
      bf16x8 bfr = ((const bf16x8*)w1f)[(nf * 6 + ks) * 64 + l];
      acc1[nfi] = __builtin_amdgcn_mfma_f32_16x16x32_bf16(af, bfr, acc1[nfi], 0, 0, 0);
    }
  }

  {
    unsigned short* ldsHu = (unsigned short*)ldsH;
#pragma unroll
    for (int nfi = 0; nfi < 6; ++nfi) {
      int hc = (w * 6 + nfi) * 16 + (l & 15);
      float bs = b1[hc];
#pragma unroll
      for (int j = 0; j < 4; ++j) {
        int pix = (l >> 4) * 4 + j;
        float x = acc1[nfi][j] + bs;
        float gl = 0.5f * x * (1.f + erff(x * 0.70710678118654752f));
        ldsHu[pix * 392 + hc] = bf16_of(gl);
      }
    }
  }
  __syncthreads();

  f32x4 acc2[3];
#pragma unroll
  for (int a = 0; a < 3; ++a) acc2[a] = (f32x4){0.f, 0.f, 0.f, 0.f};
#pragma unroll
  for (int ks = 0; ks < 12; ++ks) {
    bf16x8 af = *(const bf16x8*)&ldsH[(l & 15) * 196 + ks * 16 + (l >> 4) * 4];
#pragma unroll
    for (int nfi = 0; nfi < 3; ++nfi) {
      int nf = w * 3 + nfi;
      bf16x8 bfr = ((const bf16x8*)w2f)[(nf * 12 + ks) * 64 + l];
      acc2[nfi] = __builtin_amdgcn_mfma_f32_16x16x32_bf16(af, bfr, acc2[nfi], 0, 0, 0);
    }
  }

#pragma unroll
  for (int nfi = 0; nfi < 3; ++nfi) {
    int oc = (w * 3 + nfi) * 16 + (l & 15);
    float bs = b2[oc];
#pragma unroll
    for (int j = 0; j < 4; ++j) {
      int pix = (l >> 4) * 4 + j;
      float res = o_ws[((size_t)(b * HW) + n0 + pix) * 192 + oc];
      out[((size_t)b * 192 + oc) * HW + n0 + pix] = acc2[nfi][j] + bs + res;
    }
  }
}

extern "C" void kernel_launch(void* const* d_in, const int* in_sizes, int n_in,
                              void* d_out, int out_size, void* d_ws, size_t ws_size,
                              hipStream_t stream) {
  const float* q = (const float*)d_in[0];
  const float* k = (const float*)d_in[1];
  const float* v = (const float*)d_in[2];
  const float* offset = (const float*)d_in[3];
  const float* wq = (const float*)d_in[4];
  const float* bq = (const float*)d_in[5];
  const float* wk = (const float*)d_in[6];
  const float* bk = (const float*)d_in[7];
  const float* wv = (const float*)d_in[8];
  const float* bv = (const float*)d_in[9];
  const float* w1 = (const float*)d_in[10];
  const float* b1 = (const float*)d_in[11];
  const float* w2 = (const float*)d_in[12];
  const float* b2 = (const float*)d_in[13];
  float* out = (float*)d_out;

  float* qp_t = (float*)d_ws;                                    // 4*2304*192 f32
  float* o_ws = qp_t + (size_t)4 * HW * 192;                     // 4*2304*192 f32
  unsigned short* kvh = (unsigned short*)(o_ws + (size_t)4 * HW * 192);  // 8*2304*384 u16
  unsigned* wfb = (unsigned*)(kvh + (size_t)8 * HW * 384);       // 504*256 u32

  dim3 blk(256);
  prep_w<<<dim3(126), blk, 0, stream>>>(wq, wk, wv, w1, w2, wfb);
  proj_mfma<<<dim3(36, 20), blk, 0, stream>>>(q, k, v, wfb, bq, bk, bv, qp_t, kvh);
  attn_kernel<<<dim3(1728), blk, 0, stream>>>(qp_t, kvh, offset, o_ws);
  mlp_mfma<<<dim3(576), blk, 0, stream>>>(o_ws, wfb, b1, b2, out);
}